// Round 5
// baseline (22372.368 us; speedup 1.0000x reference)
//
#include <hip/hip_runtime.h>
#include <stdint.h>
#include <math.h>

// ---------------------------------------------------------------------------
// NMT seq2seq: encoder LSTM (S=1024) -> decoder LSTM + local attention (T=64)
// -> fused projection/log-softmax NLL.
//
// Round 9: per-batch-local scan -- ZERO cross-WG synchronization.
// The sync-latency wall (rounds 4-8: ~3.6us/step of barrier/sentinel MALL
// round trips) existed only because H=512 was sharded across 64 WGs.  Now:
// 32 WGs x 512 threads, WG b owns batch b end-to-end; thread u owns hidden
// unit u and computes all 4 of its gate rows (full 2048x512 matvec per WG
// per step).  h lives in LDS (uniform-address broadcast reads), c in a
// register, weights stream from L2 (2MB/step/WG, ~4 WGs/XCD share the same
// lines).  Weights are re-packed [kb][n][8] so the four per-gate 16B loads
// are lane-coalesced (consecutive u -> consecutive 16B), with the kb-uniform
// base advancing in an SGPR.  The decoder (gates, pt, local attention, ct,
// ct2ht) is also fully batch-local.  Only intra-WG barriers remain: this
// kernel cannot deadlock and has no cross-XCD memory-scope assumptions.
// h_hist is written and later read by the SAME WG (plain cached ops).
// ---------------------------------------------------------------------------

typedef _Float16 f16;
typedef _Float16 f16x2 __attribute__((ext_vector_type(2)));

union V8 { f16x2 p[4]; float4 f4; };

__device__ __forceinline__ float dot2f(f16x2 a, f16x2 b, float c) {
#if __has_builtin(__builtin_amdgcn_fdot2)
    return __builtin_amdgcn_fdot2(a, b, c, false);
#else
    return c + (float)a[0] * (float)b[0] + (float)a[1] * (float)b[1];
#endif
}

__device__ __forceinline__ float sigf(float x) { return 1.0f / (1.0f + __expf(-x)); }

__device__ __forceinline__ float tanh_f(float x) {
    float ax = fminf(fabsf(x), 12.0f);
    float e  = __expf(2.0f * ax);
    float r  = (e - 1.0f) / (e + 1.0f);
    return copysignf(r, x);
}

// ---------------------------------------------------------------------------
__global__ void init_accum(float* se, float* tl) {
    int i = blockIdx.x * blockDim.x + threadIdx.x;
    if (i < 2048) { se[i] = 0.0f; tl[i] = 0.0f; }
}

// ---------------------------------------------------------------------------
// Pack weights for the per-batch scan:
//   Wenc/Wdih/Wdhh : [kb=64][n=2048][8]  w[n][kb*8+kj]   (f16)
//   T2l            : [kb=64][u=512][8]   ht2tan[u][kb*8+kj]
//   CT2l           : [kb=128][u=512][8]  ct2ht[u][kb*8+kj]
// so one float4 (= 8 f16, one k-octet of one row) sits at float4-index
// kb*ROWS + n, and consecutive threads (consecutive n) read consecutive 16B.
// ---------------------------------------------------------------------------
__global__ void convert_weights(const float* __restrict__ encWhh,
                                const float* __restrict__ decWih,
                                const float* __restrict__ decWhh,
                                const float* __restrict__ ht2tan,
                                const float* __restrict__ ct2ht,
                                f16* __restrict__ Wenc, f16* __restrict__ Wdih,
                                f16* __restrict__ Wdhh, f16* __restrict__ T2l,
                                f16* __restrict__ CT2l) {
    const int NW = 2048 * 512;          // elements per big matrix
    const int NT = 512 * 512;
    const int NC = 512 * 1024;
    const int total = 3 * NW + NT + NC;
    int i = blockIdx.x * blockDim.x + threadIdx.x;
    int st = gridDim.x * blockDim.x;
    for (; i < total; i += st) {
        if (i < NW) {
            int kb = i >> 14, n = (i >> 3) & 2047, kj = i & 7;
            Wenc[i] = (f16)encWhh[n * 512 + kb * 8 + kj];
        } else if (i < 2 * NW) {
            int j = i - NW;
            int kb = j >> 14, n = (j >> 3) & 2047, kj = j & 7;
            Wdih[j] = (f16)decWih[n * 1024 + 512 + kb * 8 + kj];  // ht half of concat
        } else if (i < 3 * NW) {
            int j = i - 2 * NW;
            int kb = j >> 14, n = (j >> 3) & 2047, kj = j & 7;
            Wdhh[j] = (f16)decWhh[n * 512 + kb * 8 + kj];
        } else if (i < 3 * NW + NT) {
            int j = i - 3 * NW;
            int kb = j >> 12, u = (j >> 3) & 511, kj = j & 7;
            T2l[j] = (f16)ht2tan[u * 512 + kb * 8 + kj];
        } else {
            int j = i - 3 * NW - NT;
            int kb = j >> 12, u = (j >> 3) & 511, kj = j & 7;
            CT2l[j] = (f16)ct2ht[u * 1024 + kb * 8 + kj];
        }
    }
}

// ---------------------------------------------------------------------------
// 64x64-tile f32 GEMM, gathered A rows, bias, row-major output:
// out[r][n] = emb[idx[r]] . W[n][:] + bias[n],  out row stride 2048.
// ---------------------------------------------------------------------------
template <typename OutT>
__global__ __launch_bounds__(256) void gemm_gather(
    const float* __restrict__ emb, const int* __restrict__ idx,
    const float* __restrict__ W, int ldw,
    const float* __restrict__ bias, OutT* __restrict__ out) {
    __shared__ float As[16][65];
    __shared__ float Bs[16][65];
    const int tid = threadIdx.x;
    const int n0 = blockIdx.x * 64;
    const int r0 = blockIdx.y * 64;
    const int tx = tid & 15, ty = tid >> 4;
    const int lk = tid & 3,  lr = tid >> 2;
    const float* arow = emb + (size_t)idx[r0 + lr] * 512 + lk * 4;
    const float* brow = W + (size_t)(n0 + lr) * ldw + lk * 4;
    float acc[4][4] = {};
    for (int k0 = 0; k0 < 512; k0 += 16) {
        float4 av = *(const float4*)(arow + k0);
        float4 bv = *(const float4*)(brow + k0);
        __syncthreads();
        As[lk * 4 + 0][lr] = av.x; As[lk * 4 + 1][lr] = av.y;
        As[lk * 4 + 2][lr] = av.z; As[lk * 4 + 3][lr] = av.w;
        Bs[lk * 4 + 0][lr] = bv.x; Bs[lk * 4 + 1][lr] = bv.y;
        Bs[lk * 4 + 2][lr] = bv.z; Bs[lk * 4 + 3][lr] = bv.w;
        __syncthreads();
#pragma unroll
        for (int k = 0; k < 16; k++) {
            float a4[4], b4[4];
#pragma unroll
            for (int i = 0; i < 4; i++) a4[i] = As[k][ty * 4 + i];
#pragma unroll
            for (int j = 0; j < 4; j++) b4[j] = Bs[k][tx * 4 + j];
#pragma unroll
            for (int i = 0; i < 4; i++)
#pragma unroll
                for (int j = 0; j < 4; j++) acc[i][j] = fmaf(a4[i], b4[j], acc[i][j]);
        }
    }
#pragma unroll
    for (int j = 0; j < 4; j++) {
        int n = n0 + tx * 4 + j;
        float bv2 = bias[n];
#pragma unroll
        for (int i = 0; i < 4; i++) {
            int r = r0 + ty * 4 + i;
            out[(size_t)r * 2048 + n] = (OutT)(acc[i][j] + bv2);
        }
    }
}

// ---------------------------------------------------------------------------
// Per-batch scan: 32 WGs x 512 threads.  WG b = batch b; thread u = unit u.
// ---------------------------------------------------------------------------
__global__ __launch_bounds__(512) void scan_kernel(
    const f16* __restrict__ eg,      // [1024*32][2048]  gate pre-acts (enc)
    const float* __restrict__ dg,    // [64*32][2048]    gate pre-acts (dec, y-emb part)
    const float4* __restrict__ Wenc4, // packed [64][2048][8] f16
    const float4* __restrict__ Wdih4, // packed [64][2048][8]
    const float4* __restrict__ Wdhh4, // packed [64][2048][8]
    const float4* __restrict__ T2l4,  // packed [64][512][8]
    const float4* __restrict__ CT2l4, // packed [128][512][8]
    const float* __restrict__ wpt,   // [512]
    f16* __restrict__ h_hist,        // [32][1025][512]
    float* __restrict__ dout) {      // [2048][512]
    const int b = blockIdx.x;
    const int u = threadIdx.x;

    f16* hist = h_hist + (size_t)b * 1025 * 512;

    __shared__ __align__(16) f16 hbuf[512];    // LSTM hidden h
    __shared__ __align__(16) f16 qbuf[512];    // attention ht (decoder)
    __shared__ __align__(16) f16 ctbuf[512];   // context ct (decoder)
    __shared__ float zb[512];
    __shared__ float wptS[512];
    __shared__ float spart[64 * 9];
    __shared__ float scS[64];
    __shared__ float atwS[64];
    __shared__ float ptS[1];

    wptS[u] = wpt[u];
    hbuf[u] = (f16)0.0f;
    float c = 0.0f;
    __syncthreads();

    const float4* hb4 = (const float4*)hbuf;

    // ---------------- encoder: 1024 steps, intra-WG barriers only ----------
    for (int t = 0; t < 1024; t++) {
        const f16* ge = eg + ((size_t)t * 32 + b) * 2048;
        float a0 = (float)ge[u];
        float a1 = (float)ge[512 + u];
        float a2 = (float)ge[1024 + u];
        float a3 = (float)ge[1536 + u];
        const float4* w4 = Wenc4 + u;
#pragma unroll 4
        for (int kb = 0; kb < 64; kb++) {
            V8 h8; h8.f4 = hb4[kb];
            V8 w0, w1, w2, w3;
            w0.f4 = w4[0];
            w1.f4 = w4[512];
            w2.f4 = w4[1024];
            w3.f4 = w4[1536];
            w4 += 2048;
#pragma unroll
            for (int q = 0; q < 4; q++) {
                a0 = dot2f(w0.p[q], h8.p[q], a0);
                a1 = dot2f(w1.p[q], h8.p[q], a1);
                a2 = dot2f(w2.p[q], h8.p[q], a2);
                a3 = dot2f(w3.p[q], h8.p[q], a3);
            }
        }
        float cc = sigf(a1) * c + sigf(a0) * tanh_f(a2);
        float hh = sigf(a3) * tanh_f(cc);
        c = cc;
        __syncthreads();                       // all reads of hbuf[t] done
        hbuf[u] = (f16)hh;
        hist[(size_t)(t + 1) * 512 + u] = (f16)hh;   // same-WG read later
        __syncthreads();                       // hbuf[t+1] ready
    }

    // ---------------- decoder: 64 steps, batch-local ------------------------
    qbuf[u] = (f16)0.0f;                       // ht0 = 0
    __syncthreads();
    const float4* qb4 = (const float4*)qbuf;
    const float4* cb4 = (const float4*)ctbuf;

    for (int t = 0; t < 64; t++) {
        // ---- gates = dg + Wih_h.ht + Whh.h ----
        const float* gd = dg + ((size_t)t * 32 + b) * 2048;
        float a0 = gd[u];
        float a1 = gd[512 + u];
        float a2 = gd[1024 + u];
        float a3 = gd[1536 + u];
        {
            const float4* wq4 = Wdih4 + u;
            const float4* wh4 = Wdhh4 + u;
#pragma unroll 2
            for (int kb = 0; kb < 64; kb++) {
                V8 q8, h8; q8.f4 = qb4[kb]; h8.f4 = hb4[kb];
                V8 x0, x1, x2, x3, y0, y1, y2, y3;
                x0.f4 = wq4[0];   y0.f4 = wh4[0];
                x1.f4 = wq4[512]; y1.f4 = wh4[512];
                x2.f4 = wq4[1024]; y2.f4 = wh4[1024];
                x3.f4 = wq4[1536]; y3.f4 = wh4[1536];
                wq4 += 2048; wh4 += 2048;
#pragma unroll
                for (int q = 0; q < 4; q++) {
                    a0 = dot2f(x0.p[q], q8.p[q], a0); a0 = dot2f(y0.p[q], h8.p[q], a0);
                    a1 = dot2f(x1.p[q], q8.p[q], a1); a1 = dot2f(y1.p[q], h8.p[q], a1);
                    a2 = dot2f(x2.p[q], q8.p[q], a2); a2 = dot2f(y2.p[q], h8.p[q], a2);
                    a3 = dot2f(x3.p[q], q8.p[q], a3); a3 = dot2f(y3.p[q], h8.p[q], a3);
                }
            }
        }
        float cc = sigf(a1) * c + sigf(a0) * tanh_f(a2);
        float yt = sigf(a3) * tanh_f(cc);      // new LSTM hidden = yt
        c = cc;
        __syncthreads();                       // readers of old hbuf/qbuf done
        hbuf[u] = (f16)yt;
        __syncthreads();                       // yt visible in LDS

        // ---- z = tanh(T2l . yt); pt = sig(wpt . z) ----
        {
            float z = 0.0f;
            const float4* t4 = T2l4 + u;
#pragma unroll 4
            for (int kb = 0; kb < 64; kb++) {
                V8 y8; y8.f4 = hb4[kb];
                V8 w; w.f4 = t4[0];
                t4 += 512;
#pragma unroll
                for (int q = 0; q < 4; q++) z = dot2f(w.p[q], y8.p[q], z);
            }
            zb[u] = tanh_f(z);
        }
        __syncthreads();
        if (u < 64) {
            float pp = 0.0f;
#pragma unroll
            for (int j = 0; j < 8; j++) pp += zb[u * 8 + j] * wptS[u * 8 + j];
#pragma unroll
            for (int off = 32; off > 0; off >>= 1) pp += __shfl_down(pp, off);
            if (u == 0) ptS[0] = pp;
        }
        __syncthreads();

        // ---- window ----
        float pt = sigf(ptS[0]);
        float center = 1024.0f * pt;
        int ci = (int)floorf(center);
        int left = max(0, ci - 32);
        int right = min(1024, ci + 32);
        int win = right - left;

        // ---- scores s[p] = yt . encode_h[left+p] ----
        {
            int p = u >> 3, seg = u & 7;
            if (p < win) {
                const f16* yr = hbuf + seg * 64;
                const f16* er = hist + (size_t)(left + p + 1) * 512 + seg * 64;
                float s = 0.0f;
#pragma unroll
                for (int k = 0; k < 64; k += 8) {
                    V8 aa, bb;
                    aa.f4 = *(const float4*)(yr + k);
                    bb.f4 = *(const float4*)(er + k);
#pragma unroll
                    for (int q = 0; q < 4; q++) s = dot2f(aa.p[q], bb.p[q], s);
                }
                spart[p * 9 + seg] = s;
            }
        }
        __syncthreads();
        if (u < 64) {
            float s = -1e30f;
            if (u < win) {
                s = 0.0f;
#pragma unroll
                for (int x = 0; x < 8; x++) s += spart[u * 9 + x];
            }
            scS[u] = s;
        }
        __syncthreads();

        // ---- softmax * gauss ----
        {
            float mx = -1e30f;
            for (int q2 = 0; q2 < 64; q2++) mx = fmaxf(mx, scS[q2]);
            float sum = 0.0f;
            for (int q2 = 0; q2 < 64; q2++) sum += __expf(scS[q2] - mx);
            if (u < 64) {
                float sp = (float)(left + u) - center;
                float gs = __expf(-(sp * sp) * (1.0f / 512.0f));
                atwS[u] = (u < win) ? (__expf(scS[u] - mx) / sum) * gs : 0.0f;
            }
        }
        __syncthreads();

        // ---- ct[u] = sum_p atw[p] * encode_h[left+p][u] ----
        {
            float a = 0.0f;
            const f16* ebase = hist + (size_t)(left + 1) * 512 + u;
            for (int p2 = 0; p2 < win; p2++)
                a += atwS[p2] * (float)ebase[(size_t)p2 * 512];
            ctbuf[u] = (f16)a;
        }
        __syncthreads();

        // ---- ht_new = tanh(CT2l . [ct, yt]) ----
        {
            float s = 0.0f;
            const float4* c4 = CT2l4 + u;
#pragma unroll 2
            for (int kb = 0; kb < 64; kb++) {
                V8 x8, y8; x8.f4 = cb4[kb]; y8.f4 = hb4[kb];
                V8 w1, w2;
                w1.f4 = c4[(size_t)kb * 512];
                w2.f4 = c4[(size_t)(kb + 64) * 512];
#pragma unroll
                for (int q = 0; q < 4; q++) {
                    s = dot2f(w1.p[q], x8.p[q], s);
                    s = dot2f(w2.p[q], y8.p[q], s);
                }
            }
            float ht = tanh_f(s);
            qbuf[u] = (f16)ht;                 // safe: qbuf readers passed 2 barriers ago
            dout[((size_t)t * 32 + b) * 512 + u] = ht;
        }
        __syncthreads();                       // qbuf[t+1] ready
    }
}

// ---------------------------------------------------------------------------
// Projection + fused exp-sum / target-logit extraction.
// ---------------------------------------------------------------------------
__global__ __launch_bounds__(256) void proj_lse(
    const float* __restrict__ A,      // dec_out [2048][512]
    const float* __restrict__ W,      // [32000][512]
    const int* __restrict__ target,   // [65][32]
    float* __restrict__ se, float* __restrict__ tl) {
    __shared__ float As[16][65];
    __shared__ float Bs[16][65];
    __shared__ float eb[64][17];
    const int tid = threadIdx.x;
    const int v0 = blockIdx.x * 64;
    const int r0 = blockIdx.y * 64;
    const int tx = tid & 15, ty = tid >> 4;
    const int lk = tid & 3,  lr = tid >> 2;
    const float* arow = A + (size_t)(r0 + lr) * 512 + lk * 4;
    const float* brow = W + (size_t)(v0 + lr) * 512 + lk * 4;
    float acc[4][4] = {};
    for (int k0 = 0; k0 < 512; k0 += 16) {
        float4 av = *(const float4*)(arow + k0);
        float4 bv = *(const float4*)(brow + k0);
        __syncthreads();
        As[lk * 4 + 0][lr] = av.x; As[lk * 4 + 1][lr] = av.y;
        As[lk * 4 + 2][lr] = av.z; As[lk * 4 + 3][lr] = av.w;
        Bs[lk * 4 + 0][lr] = bv.x; Bs[lk * 4 + 1][lr] = bv.y;
        Bs[lk * 4 + 2][lr] = bv.z; Bs[lk * 4 + 3][lr] = bv.w;
        __syncthreads();
#pragma unroll
        for (int k = 0; k < 16; k++) {
            float a4[4], b4[4];
#pragma unroll
            for (int i = 0; i < 4; i++) a4[i] = As[k][ty * 4 + i];
#pragma unroll
            for (int j = 0; j < 4; j++) b4[j] = Bs[k][tx * 4 + j];
#pragma unroll
            for (int i = 0; i < 4; i++)
#pragma unroll
                for (int j = 0; j < 4; j++) acc[i][j] = fmaf(a4[i], b4[j], acc[i][j]);
        }
    }
#pragma unroll
    for (int i = 0; i < 4; i++) {
        int rg = r0 + ty * 4 + i;
        int tg = target[32 + rg];
        float es = 0.0f;
#pragma unroll
        for (int j = 0; j < 4; j++) {
            int n = v0 + tx * 4 + j;
            float l = acc[i][j];
            if (n == tg) atomicAdd(&tl[rg], l);
            es += __expf(l);
        }
        eb[ty * 4 + i][tx] = es;
    }
    __syncthreads();
    if (tid < 64) {
        float s = 0.0f;
#pragma unroll
        for (int x = 0; x < 16; x++) s += eb[tid][x];
        atomicAdd(&se[r0 + tid], s);
    }
}

__global__ void finalize_out(const float* __restrict__ se, const float* __restrict__ tl,
                             const int* __restrict__ target, float* __restrict__ out) {
    int b = threadIdx.x;
    if (b >= 32) return;
    float s = 0.0f;
    for (int t = 0; t < 64; t++) {
        int r = t * 32 + b;
        int tg = target[(t + 1) * 32 + b];
        if (tg != 0) s += tl[r] - logf(se[r]);
    }
    out[b] = s;
}

// ---------------------------------------------------------------------------
extern "C" void kernel_launch(void* const* d_in, const int* in_sizes, int n_in,
                              void* d_out, int out_size, void* d_ws, size_t ws_size,
                              hipStream_t stream) {
    const int*   source   = (const int*)  d_in[0];
    const int*   target   = (const int*)  d_in[1];
    const float* src_emb  = (const float*)d_in[2];
    const float* tar_emb  = (const float*)d_in[3];
    const float* enc_Wih  = (const float*)d_in[4];
    const float* enc_Whh  = (const float*)d_in[5];
    const float* enc_b    = (const float*)d_in[6];
    const float* dec_Wih  = (const float*)d_in[7];
    const float* dec_Whh  = (const float*)d_in[8];
    const float* dec_b    = (const float*)d_in[9];
    const float* W_ht2tan = (const float*)d_in[10];
    const float* W_tan2pt = (const float*)d_in[11];
    const float* W_ct2ht  = (const float*)d_in[12];
    const float* W_final  = (const float*)d_in[13];
    float* out = (float*)d_out;

    char* ws = (char*)d_ws;
    size_t off = 0;
    auto alloc = [&](size_t bytes) -> char* {
        char* p = ws + off;
        off = (off + bytes + 255) & ~(size_t)255;
        return p;
    };
    f16*   h_hist = (f16*)  alloc((size_t)32 * 1025 * 512 * 2);   // 33.6 MB
    float* se     = (float*)alloc((size_t)2048 * 4);
    float* tl     = (float*)alloc((size_t)2048 * 4);
    f16*   eg     = (f16*)  alloc((size_t)32768 * 2048 * 2);      // 134 MB
    float* dg     = (float*)alloc((size_t)2048 * 2048 * 4);       // 16.8 MB
    f16*   Wenc   = (f16*)  alloc((size_t)2048 * 512 * 2);
    f16*   Wdih   = (f16*)  alloc((size_t)2048 * 512 * 2);
    f16*   Wdhh   = (f16*)  alloc((size_t)2048 * 512 * 2);
    f16*   T2l    = (f16*)  alloc((size_t)512 * 512 * 2);
    f16*   CT2l   = (f16*)  alloc((size_t)512 * 1024 * 2);
    float* dout   = (float*)alloc((size_t)2048 * 512 * 4);

    init_accum<<<8, 256, 0, stream>>>(se, tl);
    convert_weights<<<2048, 256, 0, stream>>>(enc_Whh, dec_Wih, dec_Whh, W_ht2tan, W_ct2ht,
                                              Wenc, Wdih, Wdhh, T2l, CT2l);
    gemm_gather<f16><<<dim3(32, 512), 256, 0, stream>>>(src_emb, source, enc_Wih, 512,
                                                        enc_b, eg);
    gemm_gather<float><<<dim3(32, 32), 256, 0, stream>>>(tar_emb, target, dec_Wih, 1024,
                                                         dec_b, dg);
    scan_kernel<<<32, 512, 0, stream>>>(eg, dg, (const float4*)Wenc, (const float4*)Wdih,
                                        (const float4*)Wdhh, (const float4*)T2l,
                                        (const float4*)CT2l, W_tan2pt, h_hist, dout);
    proj_lse<<<dim3(500, 32), 256, 0, stream>>>(dout, W_final, target, se, tl);
    finalize_out<<<1, 64, 0, stream>>>(se, tl, target, out);
}

// Round 6
// 6354.946 us; speedup vs baseline: 3.5205x; 3.5205x over previous
//
#include <hip/hip_runtime.h>
#include <stdint.h>
#include <math.h>

// ---------------------------------------------------------------------------
// NMT seq2seq: encoder LSTM (S=1024) -> decoder LSTM + local attention (T=64)
// -> fused projection/log-softmax NLL.
//
// Round 10: round-7 scan (verified: sentinel-polled sync, 5.64ms) restored
// VERBATIM; the two ~68-GFLOP f32-FMA GEMMs (eg pre-activations, final
// projection) moved to f16 MFMA (mfma_f32_16x16x32_f16, 64x64 tile, 4 waves).
// W_final is converted to f16 into the eg buffer AFTER scan consumes eg
// (no extra workspace).  dout is now f16.  C/D fragment map (verified on
// gfx950): col = lane&15, row = (lane>>4)*4 + reg.
// ---------------------------------------------------------------------------

typedef _Float16 f16;
typedef _Float16 f16x2 __attribute__((ext_vector_type(2)));
typedef _Float16 f16x4v __attribute__((ext_vector_type(4)));
typedef _Float16 f16x8v __attribute__((ext_vector_type(8)));
typedef float    f32x4v __attribute__((ext_vector_type(4)));
typedef int i32x4 __attribute__((ext_vector_type(4)));

union V8 { f16x2 p[4]; float4 f4; };

#define CH  4            // independent batch chains
#define WPC 64           // workgroups per chain

__device__ __forceinline__ float dot2f(f16x2 a, f16x2 b, float c) {
#if __has_builtin(__builtin_amdgcn_fdot2)
    return __builtin_amdgcn_fdot2(a, b, c, false);
#else
    return c + (float)a[0] * (float)b[0] + (float)a[1] * (float)b[1];
#endif
}

__device__ __forceinline__ float sigf(float x) { return 1.0f / (1.0f + __expf(-x)); }

__device__ __forceinline__ float tanh_f(float x) {
    float ax = fminf(fabsf(x), 12.0f);
    float e  = __expf(2.0f * ax);
    float r  = (e - 1.0f) / (e + 1.0f);
    return copysignf(r, x);
}

// write-through stores: bypass L1/L2, land at coherence point (MALL)
__device__ __forceinline__ void st_wt_b16(f16* p, f16 v) {
    union { f16 h; uint16_t u; } cv; cv.h = v;
    uint32_t d = cv.u;
    asm volatile("global_store_short %0, %1, off sc0 sc1" :: "v"(p), "v"(d) : "memory");
}
__device__ __forceinline__ void st_wt_f32(float* p, float v) {
    union { float f; int i; } cv; cv.f = v;
    asm volatile("global_store_dword %0, %1, off sc0 sc1" :: "v"(p), "v"(cv.i) : "memory");
}
__device__ __forceinline__ void st_wt_b128(i32x4* p, i32x4 v) {
    asm volatile("global_store_dwordx4 %0, %1, off sc0 sc1" :: "v"(p), "v"(v) : "memory");
}
// bypass loads: straight from MALL, never L1/L2 (so polling can't see stale)
__device__ __forceinline__ i32x4 ld_bypass4(const void* p) {
    i32x4 v;
    asm volatile("global_load_dwordx4 %0, %1, off sc0 sc1\n\ts_waitcnt vmcnt(0)"
                 : "=v"(v) : "v"(p) : "memory");
    return v;
}
__device__ __forceinline__ unsigned ld_bypass_u32(const void* p) {
    unsigned v;
    asm volatile("global_load_dword %0, %1, off sc0 sc1\n\ts_waitcnt vmcnt(0)"
                 : "=v"(v) : "v"(p) : "memory");
    return v;
}

// 16B chunk of 8 f16s is valid iff no half equals the sentinel 0xFFFF (-NaN).
// Real values are finite (|h|<1, |ct|<=64), so 0xFFFF is unreachable.
__device__ __forceinline__ bool chunk_ok(i32x4 v) {
    unsigned a = ~(unsigned)v[0], b = ~(unsigned)v[1];
    unsigned c = ~(unsigned)v[2], d = ~(unsigned)v[3];
    unsigned ok = (unsigned)((a & 0xFFFFu) != 0u) & (unsigned)((a >> 16) != 0u)
                & (unsigned)((b & 0xFFFFu) != 0u) & (unsigned)((b >> 16) != 0u)
                & (unsigned)((c & 0xFFFFu) != 0u) & (unsigned)((c >> 16) != 0u)
                & (unsigned)((d & 0xFFFFu) != 0u) & (unsigned)((d >> 16) != 0u);
    return ok != 0u;
}

__device__ __forceinline__ i32x4 poll16(const f16* gp) {
    i32x4 v = ld_bypass4(gp);
    while (!chunk_ok(v)) v = ld_bypass4(gp);
    return v;
}

// gate-column permutation: global permuted col n (0..2047) -> original (4H) row.
// n = wg*32 + g*8 + uu  ->  g*512 + wg*8 + uu   (WG wg owns h-units wg*8..wg*8+8)
__device__ __forceinline__ int rowp(int n) {
    return (((n & 31) >> 3) * 512) + ((n >> 5) * 8) + (n & 7);
}

// ---------------------------------------------------------------------------
// Sentinel fill (write-through!).  h_hist/q_hist slot 0 of each chain = 0.0
// (real initial state); everything else = 0xFFFF per f16 / 0xFFFFFFFF per f32.
// ---------------------------------------------------------------------------
__global__ void fill_sentinel(i32x4* h, i32x4* q, i32x4* c, i32x4* p,
                              float* se, float* tl) {
    const size_t NH = (size_t)CH * 1089 * 512;   // h_hist in int4 units
    const size_t NQ = (size_t)CH * 65 * 512;     // q_hist
    const size_t NC = (size_t)64 * CH * 8 * 64;  // ctb
    const size_t NP = (size_t)64 * CH * 8 * 16;  // ppart (f32)
    const size_t total = NH + NQ + NC + NP;
    const i32x4 S = {-1, -1, -1, -1};
    const i32x4 Z = {0, 0, 0, 0};
    size_t stp = (size_t)gridDim.x * blockDim.x;
    for (size_t i = (size_t)blockIdx.x * blockDim.x + threadIdx.x; i < total; i += stp) {
        if (i < NH) {
            size_t r = i % (size_t)(1089 * 512);
            st_wt_b128(h + i, (r < 512) ? Z : S);
        } else if (i < NH + NQ) {
            size_t j = i - NH;
            size_t r = j % (size_t)(65 * 512);
            st_wt_b128(q + j, (r < 512) ? Z : S);
        } else if (i < NH + NQ + NC) {
            st_wt_b128(c + (i - NH - NQ), S);
        } else {
            st_wt_b128(p + (i - NH - NQ - NC), S);
        }
    }
    size_t g = (size_t)blockIdx.x * blockDim.x + threadIdx.x;
    if (g < 2048) { se[g] = 0.0f; tl[g] = 0.0f; }
}

// Convert / permute weights to f16 scan layouts.
__global__ void convert_weights(const float* __restrict__ encWhh,
                                const float* __restrict__ decWih,
                                const float* __restrict__ decWhh,
                                const float* __restrict__ ht2tan,
                                const float* __restrict__ ct2ht,
                                f16* __restrict__ Wenc, f16* __restrict__ Wdih,
                                f16* __restrict__ Wdhh, f16* __restrict__ T2l,
                                f16* __restrict__ CT2l) {
    const int NW = 2048 * 512;
    const int total = 3 * NW + 512 * 512 + 512 * 1024;
    int i = blockIdx.x * blockDim.x + threadIdx.x;
    int st = gridDim.x * blockDim.x;
    for (; i < total; i += st) {
        if (i < NW) {
            int n = i >> 9, k = i & 511;
            Wenc[i] = (f16)encWhh[rowp(n) * 512 + k];
        } else if (i < 2 * NW) {
            int j = i - NW; int n = j >> 9, k = j & 511;
            Wdih[j] = (f16)decWih[rowp(n) * 1024 + 512 + k];   // ht part of concat
        } else if (i < 3 * NW) {
            int j = i - 2 * NW; int n = j >> 9, k = j & 511;
            Wdhh[j] = (f16)decWhh[rowp(n) * 512 + k];
        } else if (i < 3 * NW + 512 * 512) {
            int j = i - 3 * NW;
            T2l[j] = (f16)ht2tan[j];
        } else {
            int j = i - 3 * NW - 512 * 512;
            CT2l[j] = (f16)ct2ht[j];
        }
    }
}

// W_final f32 -> f16 (runs AFTER scan; writes into the retired eg buffer).
__global__ void convert_wfinal(const float* __restrict__ Wf, f16* __restrict__ Wh) {
    const int total = 32000 * 512;
    int i = blockIdx.x * blockDim.x + threadIdx.x;
    int st = gridDim.x * blockDim.x;
    for (; i < total; i += st) Wh[i] = (f16)Wf[i];
}

// ---------------------------------------------------------------------------
// 64x64-tile f32 GEMM, gathered A rows, bias, scan-layout output (dg only):
// value for (row r = t*32+B, permuted col n) stored at
// [t][chain=B>>3][wg=n>>5][c=n&31][bb=B&7].
// ---------------------------------------------------------------------------
template <typename OutT>
__global__ __launch_bounds__(256) void gemm_gather(
    const float* __restrict__ emb, const int* __restrict__ idx,
    const float* __restrict__ W, int ldw,
    const float* __restrict__ bias, OutT* __restrict__ out) {
    __shared__ float As[16][65];
    __shared__ float Bs[16][65];
    const int tid = threadIdx.x;
    const int n0 = blockIdx.x * 64;
    const int r0 = blockIdx.y * 64;
    const int tx = tid & 15, ty = tid >> 4;
    const int lk = tid & 3,  lr = tid >> 2;
    const float* arow = emb + (size_t)idx[r0 + lr] * 512 + lk * 4;
    const float* brow = W + (size_t)rowp(n0 + lr) * ldw + lk * 4;
    float acc[4][4] = {};
    for (int k0 = 0; k0 < 512; k0 += 16) {
        float4 av = *(const float4*)(arow + k0);
        float4 bv = *(const float4*)(brow + k0);
        __syncthreads();
        As[lk * 4 + 0][lr] = av.x; As[lk * 4 + 1][lr] = av.y;
        As[lk * 4 + 2][lr] = av.z; As[lk * 4 + 3][lr] = av.w;
        Bs[lk * 4 + 0][lr] = bv.x; Bs[lk * 4 + 1][lr] = bv.y;
        Bs[lk * 4 + 2][lr] = bv.z; Bs[lk * 4 + 3][lr] = bv.w;
        __syncthreads();
#pragma unroll
        for (int k = 0; k < 16; k++) {
            float a4[4], b4[4];
#pragma unroll
            for (int i = 0; i < 4; i++) a4[i] = As[k][ty * 4 + i];
#pragma unroll
            for (int j = 0; j < 4; j++) b4[j] = Bs[k][tx * 4 + j];
#pragma unroll
            for (int i = 0; i < 4; i++)
#pragma unroll
                for (int j = 0; j < 4; j++) acc[i][j] = fmaf(a4[i], b4[j], acc[i][j]);
        }
    }
#pragma unroll
    for (int j = 0; j < 4; j++) {
        int n = n0 + tx * 4 + j;
        float bv2 = bias[rowp(n)];
#pragma unroll
        for (int i = 0; i < 4; i++) {
            int r = r0 + ty * 4 + i;
            int t = r >> 5, B = r & 31;
            size_t addr = ((((size_t)t * 4 + (B >> 3)) * 64 + (n >> 5)) * 32
                           + (n & 31)) * 8 + (B & 7);
            out[addr] = (OutT)(acc[i][j] + bv2);
        }
    }
}

// ---------------------------------------------------------------------------
// MFMA f16 GEMM for eg: out(r,n) = emb[idx[r]] . encWih[rowp(n)] + b[rowp(n)],
// stored f16 in scan layout.  64x64 tile, 4 waves, 16x16x32 MFMA.
// D-fragment: col = lane&15 (n), row = (lane>>4)*4 + reg (r).
// ---------------------------------------------------------------------------
__global__ __launch_bounds__(256) void gemm_eg_mfma(
    const float* __restrict__ emb, const int* __restrict__ idx,
    const float* __restrict__ W, const float* __restrict__ bias,
    f16* __restrict__ out) {
    __shared__ __align__(16) f16 Af[64][40];
    __shared__ __align__(16) f16 Bf[64][40];
    const int tid = threadIdx.x;
    const int n0 = blockIdx.x * 64;
    const int r0 = blockIdx.y * 64;
    const int srow = tid >> 2, sseg = tid & 3;
    const float* arow = emb + (size_t)idx[r0 + srow] * 512 + sseg * 8;
    const float* brow = W + (size_t)rowp(n0 + srow) * 512 + sseg * 8;
    const int w = tid >> 6, l = tid & 63;
    const int lr = l & 15, lk = l >> 4;
    f32x4v acc[4] = {};
    for (int k0 = 0; k0 < 512; k0 += 32) {
        float4 a0 = *(const float4*)(arow + k0);
        float4 a1 = *(const float4*)(arow + k0 + 4);
        float4 b0 = *(const float4*)(brow + k0);
        float4 b1 = *(const float4*)(brow + k0 + 4);
        __syncthreads();                          // prev iter frag reads done
        f16x8v av, bv;
        av[0]=(f16)a0.x; av[1]=(f16)a0.y; av[2]=(f16)a0.z; av[3]=(f16)a0.w;
        av[4]=(f16)a1.x; av[5]=(f16)a1.y; av[6]=(f16)a1.z; av[7]=(f16)a1.w;
        bv[0]=(f16)b0.x; bv[1]=(f16)b0.y; bv[2]=(f16)b0.z; bv[3]=(f16)b0.w;
        bv[4]=(f16)b1.x; bv[5]=(f16)b1.y; bv[6]=(f16)b1.z; bv[7]=(f16)b1.w;
        *(f16x8v*)&Af[srow][sseg * 8] = av;
        *(f16x8v*)&Bf[srow][sseg * 8] = bv;
        __syncthreads();
        f16x8v af = *(const f16x8v*)&Af[w * 16 + lr][lk * 8];
#pragma unroll
        for (int j = 0; j < 4; j++) {
            f16x8v bf = *(const f16x8v*)&Bf[j * 16 + lr][lk * 8];
            acc[j] = __builtin_amdgcn_mfma_f32_16x16x32_f16(af, bf, acc[j], 0, 0, 0);
        }
    }
    const int rq = r0 + w * 16 + lk * 4;          // quad base row (4-aligned)
    const int t = rq >> 5;
    const int B = rq & 31;                        // quad stays in one octet
#pragma unroll
    for (int j = 0; j < 4; j++) {
        int n = n0 + j * 16 + lr;
        float bb = bias[rowp(n)];
        f16x4v pk;
#pragma unroll
        for (int r = 0; r < 4; r++) pk[r] = (f16)(acc[j][r] + bb);
        size_t addr = ((((size_t)t * 4 + (B >> 3)) * 64 + (n >> 5)) * 32
                       + (n & 31)) * 8 + (B & 7);
        *(f16x4v*)(out + addr) = pk;              // 8B packed store
    }
}

// ---------------------------------------------------------------------------
// MFMA f16 projection + fused exp-sum / target-logit extraction.
// A = dout f16 [2048][512]; B = W_final f16 [32000][512].
// ---------------------------------------------------------------------------
__global__ __launch_bounds__(256) void proj_lse_mfma(
    const f16* __restrict__ A, const f16* __restrict__ Wh,
    const int* __restrict__ target,
    float* __restrict__ se, float* __restrict__ tl) {
    __shared__ __align__(16) f16 Af[64][40];
    __shared__ __align__(16) f16 Bf[64][40];
    const int tid = threadIdx.x;
    const int v0 = blockIdx.x * 64;
    const int r0 = blockIdx.y * 64;
    const int srow = tid >> 2, sseg = tid & 3;
    const f16* arow = A + (size_t)(r0 + srow) * 512 + sseg * 8;
    const f16* brow = Wh + (size_t)(v0 + srow) * 512 + sseg * 8;
    const int w = tid >> 6, l = tid & 63;
    const int lr = l & 15, lk = l >> 4;
    f32x4v acc[4] = {};
    for (int k0 = 0; k0 < 512; k0 += 32) {
        f16x8v av = *(const f16x8v*)(arow + k0);
        f16x8v bv = *(const f16x8v*)(brow + k0);
        __syncthreads();
        *(f16x8v*)&Af[srow][sseg * 8] = av;
        *(f16x8v*)&Bf[srow][sseg * 8] = bv;
        __syncthreads();
        f16x8v af = *(const f16x8v*)&Af[w * 16 + lr][lk * 8];
#pragma unroll
        for (int j = 0; j < 4; j++) {
            f16x8v bf = *(const f16x8v*)&Bf[j * 16 + lr][lk * 8];
            acc[j] = __builtin_amdgcn_mfma_f32_16x16x32_f16(af, bf, acc[j], 0, 0, 0);
        }
    }
#pragma unroll
    for (int r = 0; r < 4; r++) {
        int rg = r0 + w * 16 + lk * 4 + r;
        int tg = target[32 + rg];
        float es = 0.0f;
#pragma unroll
        for (int j = 0; j < 4; j++) {
            int n = v0 + j * 16 + lr;
            float lv = acc[j][r];
            if (n == tg) atomicAdd(&tl[rg], lv);
            es += __expf(lv);
        }
#pragma unroll
        for (int m = 1; m < 16; m <<= 1) es += __shfl_xor(es, m);
        if (lr == 0) atomicAdd(&se[rg], es);
    }
}

// ---------------------------------------------------------------------------
// Persistent scan (round-7, verified): 256 WGs x 512 threads = 4 chains x 64
// WGs.  All cross-WG handoffs are sentinel-polled data loads.  Only change
// vs round 7: dout is f16.
// ---------------------------------------------------------------------------
__global__ __launch_bounds__(512) void scan_kernel(
    const f16* __restrict__ eg,      // [1024][CH][64][32][8]
    const float* __restrict__ dg,    // [64][CH][64][32][8]
    const f16* __restrict__ Wenc,    // [2048][512] rows in permuted col order
    const f16* __restrict__ Wdih,    // [2048][512]
    const f16* __restrict__ Wdhh,    // [2048][512]
    const f16* __restrict__ T2l,     // [512][512]
    const f16* __restrict__ CT2l,    // [512][1024]
    const float* __restrict__ wpt,   // [512]
    f16* __restrict__ h_hist,        // [CH][1089][8][512] slot0 zero, rest sentinel
    f16* __restrict__ q_hist,        // [CH][65][8][512]  slot0 zero, rest sentinel
    f16* __restrict__ ctb,           // [64][CH][8][512]  sentinel-filled
    float* __restrict__ ppart,       // [64][CH][8][64]   sentinel-filled
    f16* __restrict__ dout) {        // [2048][512] f16
    const int bid = blockIdx.x;
    const int chain = bid >> 6;
    const int wg = bid & 63;
    const int tid = threadIdx.x;

    f16* hc = h_hist + (size_t)chain * 1089 * 4096;
    f16* qc = q_hist + (size_t)chain * 65 * 4096;

    __shared__ __align__(16) f16  Ws[32 * 520];    // 33280 B encoder weights
    __shared__ __align__(16) f16  hst[8 * 520];    //  8320 B h[t] staging
    __shared__ __align__(16) f16  qst[8 * 520];    //  prev ht staging (decoder)
    __shared__ __align__(16) f16  yst[8 * 520];    //  yt staging (decoder)
    __shared__ __align__(16) f16  ctst[8 * 520];   //  ct staging (decoder)
    __shared__ float part[512];
    __shared__ float zbS[64];
    __shared__ float spart[64 * 9];
    __shared__ float scS[64];
    __shared__ float atwS[64];
    __shared__ float ptS[1];

    // stage encoder weight slice (32 rows x 512) into LDS, 520-f16 padded rows
    {
        int r = tid >> 4, seg = tid & 15;
        const float4* s4 = (const float4*)(Wenc + (size_t)(wg * 32 + r) * 512) + seg * 4;
        float4 a0 = s4[0], a1 = s4[1], a2 = s4[2], a3 = s4[3];
        float4* d4 = (float4*)(Ws + r * 520) + seg * 4;
        d4[0] = a0; d4[1] = a1; d4[2] = a2; d4[3] = a3;
    }
    __syncthreads();

    const int c  = (tid >> 3) & 31;   // gate col (local)
    const int bq = tid & 7;           // batch (local)
    const int kh = tid >> 8;          // k half
    const int sb = tid >> 6, sj = tid & 63;   // staging: batch, 16B chunk (full row)
    const int au = tid & 7, ab = tid >> 3;    // activation: uu, bq (tid<64)
    float creg = 0.0f;                // cell state (tid<64)

    float egv = 0.0f;
    if (kh == 0)
        egv = (float)eg[(size_t)chain * 16384 + wg * 256 + c * 8 + bq];

    // ---------------- encoder: 1024 steps, ZERO barriers ----------------
    for (int t = 0; t < 1024; t++) {
        {   // poll-stage h[t] (8KB) -> LDS; chunk (sb,sj) produced by WG sj
            i32x4 v = poll16(hc + (size_t)t * 4096 + sb * 512 + sj * 8);
            *((i32x4*)(hst + sb * 520) + sj) = v;
        }
        float egn = 0.0f;
        if (kh == 0 && t < 1023)   // prefetch next step's gate (in flight thru dot)
            egn = (float)eg[((size_t)(t + 1) * 4 + chain) * 16384 + wg * 256 + c * 8 + bq];
        __syncthreads();
        {   // dot: col c, batch bq, k-half kh
            const f16* Wr = Ws + c * 520 + kh * 256;
            const f16* hr = hst + bq * 520 + kh * 256;
            float a0 = (kh == 0) ? egv : 0.0f;
#pragma unroll 8
            for (int k = 0; k < 256; k += 8) {
                V8 wv, xv;
                wv.f4 = *(const float4*)(Wr + k);
                xv.f4 = *(const float4*)(hr + k);
#pragma unroll
                for (int q = 0; q < 4; q++) a0 = dot2f(wv.p[q], xv.p[q], a0);
            }
            part[tid] = a0;
        }
        egv = egn;
        __syncthreads();
        if (tid < 64) {
            float gi = part[(au)      * 8 + ab] + part[256 + (au)      * 8 + ab];
            float gf = part[(8 + au)  * 8 + ab] + part[256 + (8 + au)  * 8 + ab];
            float gg = part[(16 + au) * 8 + ab] + part[256 + (16 + au) * 8 + ab];
            float go = part[(24 + au) * 8 + ab] + part[256 + (24 + au) * 8 + ab];
            float cc = sigf(gf) * creg + sigf(gi) * tanh_f(gg);
            float hh = sigf(go) * tanh_f(cc);
            creg = cc;
            // fire-and-forget: consumers poll the data itself
            st_wt_b16(hc + (size_t)(t + 1) * 4096 + ab * 512 + wg * 8 + au, (f16)hh);
        }
        // no barrier: next iteration's poll gates on h[t+1] arrival
    }

    // ---------------- decoder: 64 steps, ZERO barriers ----------------
    // pre-stage yst = hc[1024] (encoder final h; doubles as hsrc for t=0)
    {
        i32x4 v = poll16(hc + (size_t)1024 * 4096 + sb * 512 + sj * 8);
        *((i32x4*)(yst + sb * 520) + sj) = v;
    }

    for (int t = 0; t < 64; t++) {
        f16* ydst = hc + (size_t)(1025 + t) * 4096;       // yt slot

        // ---- stage A: gates = dg + Wih_h.ht + Whh.h; ht from qst, h from yst ----
        {   // poll-stage qc[t] (8KB) -> qst, full row coverage
            i32x4 v = poll16(qc + (size_t)t * 4096 + sb * 512 + sj * 8);
            *((i32x4*)(qst + sb * 520) + sj) = v;
        }
        __syncthreads();
        {
            float dgv = (kh == 0)
                ? dg[((size_t)t * 4 + chain) * 16384 + wg * 256 + c * 8 + bq] : 0.0f;
            const f16* W1 = Wdih + (size_t)(wg * 32 + c) * 512 + kh * 256;
            const f16* W2 = Wdhh + (size_t)(wg * 32 + c) * 512 + kh * 256;
            const f16* q0 = qst + bq * 520 + kh * 256;
            const f16* h0 = yst + bq * 520 + kh * 256;
            float a0 = dgv;
#pragma unroll 4
            for (int k = 0; k < 256; k += 8) {
                V8 w1, w2, x0, y0;
                w1.f4 = *(const float4*)(W1 + k);
                x0.f4 = *(const float4*)(q0 + k);
                w2.f4 = *(const float4*)(W2 + k);
                y0.f4 = *(const float4*)(h0 + k);
#pragma unroll
                for (int q = 0; q < 4; q++) {
                    a0 = dot2f(w1.p[q], x0.p[q], a0);
                    a0 = dot2f(w2.p[q], y0.p[q], a0);
                }
            }
            part[tid] = a0;
        }
        __syncthreads();
        if (tid < 64) {
            float gi = part[(au)      * 8 + ab] + part[256 + (au)      * 8 + ab];
            float gf = part[(8 + au)  * 8 + ab] + part[256 + (8 + au)  * 8 + ab];
            float gg = part[(16 + au) * 8 + ab] + part[256 + (16 + au) * 8 + ab];
            float go = part[(24 + au) * 8 + ab] + part[256 + (24 + au) * 8 + ab];
            float cc = sigf(gf) * creg + sigf(gi) * tanh_f(gg);
            float hh = sigf(go) * tanh_f(cc);
            creg = cc;
            st_wt_b16(ydst + ab * 512 + wg * 8 + au, (f16)hh);
        }

        // ---- stage B: poll-stage yt -> yst; z = tanh(yt @ W_ht2tan.T); pt partial ----
        {
            i32x4 v = poll16(ydst + sb * 512 + sj * 8);
            *((i32x4*)(yst + sb * 520) + sj) = v;
        }
        __syncthreads();
        {
            int kq = tid >> 6, zu = (tid >> 3) & 7, zq = tid & 7;
            const f16* Tr = T2l + (size_t)(wg * 8 + zu) * 512 + kq * 64;
            const f16* yr = yst + zq * 520 + kq * 64;
            float s = 0.0f;
#pragma unroll
            for (int k = 0; k < 64; k += 8) {
                V8 aa, bb;
                aa.f4 = *(const float4*)(Tr + k);
                bb.f4 = *(const float4*)(yr + k);
#pragma unroll
                for (int q = 0; q < 4; q++) s = dot2f(aa.p[q], bb.p[q], s);
            }
            part[tid] = s;
        }
        __syncthreads();
        if (tid < 64) {
            float z = 0.0f;
#pragma unroll
            for (int kq = 0; kq < 8; kq++) z += part[kq * 64 + tid];
            zbS[tid] = tanh_f(z);             // zbS[zu*8 + zq]
        }
        __syncthreads();
        if (tid < 8) {
            float pp = 0.0f;
#pragma unroll
            for (int u2 = 0; u2 < 8; u2++) pp += zbS[u2 * 8 + tid] * wpt[wg * 8 + u2];
            st_wt_f32(&ppart[(((size_t)t * 4 + chain) * 8 + tid) * 64 + wg], pp);
        }

        // ---- stage C: local attention (WG wg<8 owns chain-batch wg) ----
        if (wg < 8) {
            const int bb = wg;
            if (tid < 64) {
                const float* pa = ppart + (((size_t)t * 4 + chain) * 8 + bb) * 64 + tid;
                unsigned bits = ld_bypass_u32(pa);
                while (bits == 0xFFFFFFFFu) bits = ld_bypass_u32(pa);
                union { unsigned u; float f; } cv; cv.u = bits;
                float v = cv.f;
#pragma unroll
                for (int off = 32; off > 0; off >>= 1) v += __shfl_down(v, off);
                if (tid == 0) ptS[0] = v;
            }
            __syncthreads();
            float pt = sigf(ptS[0]);
            float center = 1024.0f * pt;
            int ci = (int)floorf(center);
            int left = max(0, ci - 32);
            int right = min(1024, ci + 32);
            int win = right - left;
            int p = tid >> 3, seg = tid & 7;
            if (p < win) {
                const f16* yr = yst + bb * 520 + seg * 64;
                const f16* er = hc + (size_t)(left + p + 1) * 4096 + bb * 512 + seg * 64;
                float s = 0.0f;
#pragma unroll
                for (int k = 0; k < 64; k += 8) {
                    V8 aa, bbv;
                    aa.f4  = *(const float4*)(yr + k);
                    bbv.f4 = *(const float4*)(er + k);
#pragma unroll
                    for (int q = 0; q < 4; q++) s = dot2f(aa.p[q], bbv.p[q], s);
                }
                spart[p * 9 + seg] = s;
            }
            __syncthreads();
            if (tid < 64) {
                float s = -1e30f;
                if (tid < win) {
                    s = 0.0f;
#pragma unroll
                    for (int x = 0; x < 8; x++) s += spart[tid * 9 + x];
                }
                scS[tid] = s;
            }
            __syncthreads();
            float mx = -1e30f;
            for (int q2 = 0; q2 < 64; q2++) mx = fmaxf(mx, scS[q2]);
            float sum = 0.0f;
            for (int q2 = 0; q2 < 64; q2++) sum += __expf(scS[q2] - mx);
            if (tid < 64) {
                float sp = (float)(left + tid) - center;
                float gs = __expf(-(sp * sp) * (1.0f / 512.0f));
                atwS[tid] = (tid < win) ? (__expf(scS[tid] - mx) / sum) * gs : 0.0f;
            }
            __syncthreads();
            {
                int j = tid;   // 0..511
                float a = 0.0f;
                const f16* ebase = hc + (size_t)(left + 1) * 4096 + bb * 512 + j;
                for (int p2 = 0; p2 < win; p2++)
                    a += atwS[p2] * (float)ebase[(size_t)p2 * 4096];
                st_wt_b16(ctb + ((((size_t)t * 4 + chain) * 8 + bb) * 512) + j, (f16)a);
            }
        }

        // ---- stage D: poll-stage ct -> ctst; ht_new = tanh([ct, yt] @ W_ct2ht.T) ----
        {
            i32x4 v = poll16(ctb + (((size_t)t * 4 + chain) * 8 + sb) * 512 + sj * 8);
            *((i32x4*)(ctst + sb * 520) + sj) = v;
        }
        __syncthreads();
        {
            int kq = tid >> 6, du = (tid >> 3) & 7, dq = tid & 7;
            const f16* Cr = CT2l + (size_t)(wg * 8 + du) * 1024 + kq * 128;
            const f16* xr = (kq < 4)
                ? (ctst + dq * 520 + kq * 128)
                : (yst + dq * 520 + (kq - 4) * 128);
            float s = 0.0f;
#pragma unroll 4
            for (int k = 0; k < 128; k += 8) {
                V8 aa, bb;
                aa.f4 = *(const float4*)(Cr + k);
                bb.f4 = *(const float4*)(xr + k);
#pragma unroll
                for (int q = 0; q < 4; q++) s = dot2f(aa.p[q], bb.p[q], s);
            }
            part[tid] = s;
        }
        __syncthreads();
        if (tid < 64) {
            float s = 0.0f;
#pragma unroll
            for (int kq = 0; kq < 8; kq++) s += part[kq * 64 + tid];
            float hv = tanh_f(s);
            int du = tid >> 3, dq = tid & 7;
            st_wt_b16(qc + (size_t)(t + 1) * 4096 + dq * 512 + wg * 8 + du, (f16)hv);
            dout[((size_t)t * 32 + chain * 8 + dq) * 512 + wg * 8 + du] = (f16)hv;
        }
        // no end barrier: stage A(t+1) polls qc[t+1]
    }
}

__global__ void finalize_out(const float* __restrict__ se, const float* __restrict__ tl,
                             const int* __restrict__ target, float* __restrict__ out) {
    int b = threadIdx.x;
    if (b >= 32) return;
    float s = 0.0f;
    for (int t = 0; t < 64; t++) {
        int r = t * 32 + b;
        int tg = target[(t + 1) * 32 + b];
        if (tg != 0) s += tl[r] - logf(se[r]);
    }
    out[b] = s;
}

// ---------------------------------------------------------------------------
extern "C" void kernel_launch(void* const* d_in, const int* in_sizes, int n_in,
                              void* d_out, int out_size, void* d_ws, size_t ws_size,
                              hipStream_t stream) {
    const int*   source   = (const int*)  d_in[0];
    const int*   target   = (const int*)  d_in[1];
    const float* src_emb  = (const float*)d_in[2];
    const float* tar_emb  = (const float*)d_in[3];
    const float* enc_Wih  = (const float*)d_in[4];
    const float* enc_Whh  = (const float*)d_in[5];
    const float* enc_b    = (const float*)d_in[6];
    const float* dec_Wih  = (const float*)d_in[7];
    const float* dec_Whh  = (const float*)d_in[8];
    const float* dec_b    = (const float*)d_in[9];
    const float* W_ht2tan = (const float*)d_in[10];
    const float* W_tan2pt = (const float*)d_in[11];
    const float* W_ct2ht  = (const float*)d_in[12];
    const float* W_final  = (const float*)d_in[13];
    float* out = (float*)d_out;

    char* ws = (char*)d_ws;
    size_t off = 0;
    auto alloc = [&](size_t bytes) -> char* {
        char* p = ws + off;
        off = (off + bytes + 255) & ~(size_t)255;
        return p;
    };
    f16*   h_hist = (f16*)  alloc((size_t)CH * 1089 * 4096 * 2);  // 35.7 MB
    f16*   q_hist = (f16*)  alloc((size_t)CH * 65 * 4096 * 2);
    f16*   ctb    = (f16*)  alloc((size_t)64 * CH * 8 * 512 * 2);
    float* ppart  = (float*)alloc((size_t)64 * CH * 8 * 64 * 4);
    float* se     = (float*)alloc((size_t)2048 * 4);
    float* tl     = (float*)alloc((size_t)2048 * 4);
    f16*   eg     = (f16*)  alloc((size_t)32768 * 2048 * 2);      // 128 MB
    float* dg     = (float*)alloc((size_t)2048 * 2048 * 4);       // 16 MB
    f16*   Wenc   = (f16*)  alloc((size_t)2048 * 512 * 2);
    f16*   Wdih   = (f16*)  alloc((size_t)2048 * 512 * 2);
    f16*   Wdhh   = (f16*)  alloc((size_t)2048 * 512 * 2);
    f16*   T2l    = (f16*)  alloc((size_t)512 * 512 * 2);
    f16*   CT2l   = (f16*)  alloc((size_t)512 * 1024 * 2);
    f16*   dout   = (f16*)  alloc((size_t)2048 * 512 * 2);
    f16*   Wf16   = eg;     // reuse: eg is dead after scan; 32000*512*2 = 33MB <= 128MB

    fill_sentinel<<<2048, 256, 0, stream>>>((i32x4*)h_hist, (i32x4*)q_hist,
                                            (i32x4*)ctb, (i32x4*)ppart, se, tl);
    convert_weights<<<2048, 256, 0, stream>>>(enc_Whh, dec_Wih, dec_Whh, W_ht2tan, W_ct2ht,
                                              Wenc, Wdih, Wdhh, T2l, CT2l);
    gemm_eg_mfma<<<dim3(32, 512), 256, 0, stream>>>(src_emb, source, enc_Wih, enc_b, eg);
    gemm_gather<float><<<dim3(32, 32), 256, 0, stream>>>(tar_emb, target, dec_Wih, 1024,
                                                         dec_b, dg);
    scan_kernel<<<CH * WPC, 512, 0, stream>>>(eg, dg, Wenc, Wdih, Wdhh, T2l, CT2l,
                                              W_tan2pt, h_hist, q_hist, ctb, ppart,
                                              dout);
    convert_wfinal<<<2048, 256, 0, stream>>>(W_final, Wf16);
    proj_lse_mfma<<<dim3(500, 32), 256, 0, stream>>>(dout, Wf16, target, se, tl);
    finalize_out<<<1, 64, 0, stream>>>(se, tl, target, out);
}

// Round 7
// 5931.248 us; speedup vs baseline: 3.7719x; 1.0714x over previous
//
#include <hip/hip_runtime.h>
#include <stdint.h>
#include <math.h>

// ---------------------------------------------------------------------------
// NMT seq2seq: encoder LSTM (S=1024) -> decoder LSTM + local attention (T=64)
// -> fused projection/log-softmax NLL.
//
// Round 11: round-10 (6355us) + encoder/decoder weight slices hoisted into
// VGPRs.  The encoder dot issued 64 ds_read_b128/thread/step, half of them
// re-reading the loop-invariant weight slice; now that slice (256 f16 = 128
// VGPRs) is loaded once and the per-step dot reads only h from LDS (32
// b128/thread).  After the encoder the same register block is reloaded with
// the Wdih slice for decoder stage A (invariant over 64 steps), halving its
// per-step global weight traffic.  __launch_bounds__(512, 2) caps at 2
// waves/SIMD -> 256 VGPRs, no spill.  All loops indexing the reg array are
// FULLY unrolled (runtime-indexed reg arrays go to scratch).  Accumulation
// order unchanged -> bit-exact vs round 10.  Sync structure untouched.
// ---------------------------------------------------------------------------

typedef _Float16 f16;
typedef _Float16 f16x2 __attribute__((ext_vector_type(2)));
typedef _Float16 f16x4v __attribute__((ext_vector_type(4)));
typedef _Float16 f16x8v __attribute__((ext_vector_type(8)));
typedef float    f32x4v __attribute__((ext_vector_type(4)));
typedef int i32x4 __attribute__((ext_vector_type(4)));

union V8 { f16x2 p[4]; float4 f4; };

#define CH  4            // independent batch chains
#define WPC 64           // workgroups per chain

__device__ __forceinline__ float dot2f(f16x2 a, f16x2 b, float c) {
#if __has_builtin(__builtin_amdgcn_fdot2)
    return __builtin_amdgcn_fdot2(a, b, c, false);
#else
    return c + (float)a[0] * (float)b[0] + (float)a[1] * (float)b[1];
#endif
}

__device__ __forceinline__ float sigf(float x) { return 1.0f / (1.0f + __expf(-x)); }

__device__ __forceinline__ float tanh_f(float x) {
    float ax = fminf(fabsf(x), 12.0f);
    float e  = __expf(2.0f * ax);
    float r  = (e - 1.0f) / (e + 1.0f);
    return copysignf(r, x);
}

// write-through stores: bypass L1/L2, land at coherence point (MALL)
__device__ __forceinline__ void st_wt_b16(f16* p, f16 v) {
    union { f16 h; uint16_t u; } cv; cv.h = v;
    uint32_t d = cv.u;
    asm volatile("global_store_short %0, %1, off sc0 sc1" :: "v"(p), "v"(d) : "memory");
}
__device__ __forceinline__ void st_wt_f32(float* p, float v) {
    union { float f; int i; } cv; cv.f = v;
    asm volatile("global_store_dword %0, %1, off sc0 sc1" :: "v"(p), "v"(cv.i) : "memory");
}
__device__ __forceinline__ void st_wt_b128(i32x4* p, i32x4 v) {
    asm volatile("global_store_dwordx4 %0, %1, off sc0 sc1" :: "v"(p), "v"(v) : "memory");
}
// bypass loads: straight from MALL, never L1/L2 (so polling can't see stale)
__device__ __forceinline__ i32x4 ld_bypass4(const void* p) {
    i32x4 v;
    asm volatile("global_load_dwordx4 %0, %1, off sc0 sc1\n\ts_waitcnt vmcnt(0)"
                 : "=v"(v) : "v"(p) : "memory");
    return v;
}
__device__ __forceinline__ unsigned ld_bypass_u32(const void* p) {
    unsigned v;
    asm volatile("global_load_dword %0, %1, off sc0 sc1\n\ts_waitcnt vmcnt(0)"
                 : "=v"(v) : "v"(p) : "memory");
    return v;
}

// 16B chunk of 8 f16s is valid iff no half equals the sentinel 0xFFFF (-NaN).
// Real values are finite (|h|<1, |ct|<=64), so 0xFFFF is unreachable.
__device__ __forceinline__ bool chunk_ok(i32x4 v) {
    unsigned a = ~(unsigned)v[0], b = ~(unsigned)v[1];
    unsigned c = ~(unsigned)v[2], d = ~(unsigned)v[3];
    unsigned ok = (unsigned)((a & 0xFFFFu) != 0u) & (unsigned)((a >> 16) != 0u)
                & (unsigned)((b & 0xFFFFu) != 0u) & (unsigned)((b >> 16) != 0u)
                & (unsigned)((c & 0xFFFFu) != 0u) & (unsigned)((c >> 16) != 0u)
                & (unsigned)((d & 0xFFFFu) != 0u) & (unsigned)((d >> 16) != 0u);
    return ok != 0u;
}

__device__ __forceinline__ i32x4 poll16(const f16* gp) {
    i32x4 v = ld_bypass4(gp);
    while (!chunk_ok(v)) v = ld_bypass4(gp);
    return v;
}

// gate-column permutation: global permuted col n (0..2047) -> original (4H) row.
// n = wg*32 + g*8 + uu  ->  g*512 + wg*8 + uu   (WG wg owns h-units wg*8..wg*8+8)
__device__ __forceinline__ int rowp(int n) {
    return (((n & 31) >> 3) * 512) + ((n >> 5) * 8) + (n & 7);
}

// ---------------------------------------------------------------------------
// Sentinel fill (write-through!).  h_hist/q_hist slot 0 of each chain = 0.0
// (real initial state); everything else = 0xFFFF per f16 / 0xFFFFFFFF per f32.
// ---------------------------------------------------------------------------
__global__ void fill_sentinel(i32x4* h, i32x4* q, i32x4* c, i32x4* p,
                              float* se, float* tl) {
    const size_t NH = (size_t)CH * 1089 * 512;   // h_hist in int4 units
    const size_t NQ = (size_t)CH * 65 * 512;     // q_hist
    const size_t NC = (size_t)64 * CH * 8 * 64;  // ctb
    const size_t NP = (size_t)64 * CH * 8 * 16;  // ppart (f32)
    const size_t total = NH + NQ + NC + NP;
    const i32x4 S = {-1, -1, -1, -1};
    const i32x4 Z = {0, 0, 0, 0};
    size_t stp = (size_t)gridDim.x * blockDim.x;
    for (size_t i = (size_t)blockIdx.x * blockDim.x + threadIdx.x; i < total; i += stp) {
        if (i < NH) {
            size_t r = i % (size_t)(1089 * 512);
            st_wt_b128(h + i, (r < 512) ? Z : S);
        } else if (i < NH + NQ) {
            size_t j = i - NH;
            size_t r = j % (size_t)(65 * 512);
            st_wt_b128(q + j, (r < 512) ? Z : S);
        } else if (i < NH + NQ + NC) {
            st_wt_b128(c + (i - NH - NQ), S);
        } else {
            st_wt_b128(p + (i - NH - NQ - NC), S);
        }
    }
    size_t g = (size_t)blockIdx.x * blockDim.x + threadIdx.x;
    if (g < 2048) { se[g] = 0.0f; tl[g] = 0.0f; }
}

// Convert / permute weights to f16 scan layouts.
__global__ void convert_weights(const float* __restrict__ encWhh,
                                const float* __restrict__ decWih,
                                const float* __restrict__ decWhh,
                                const float* __restrict__ ht2tan,
                                const float* __restrict__ ct2ht,
                                f16* __restrict__ Wenc, f16* __restrict__ Wdih,
                                f16* __restrict__ Wdhh, f16* __restrict__ T2l,
                                f16* __restrict__ CT2l) {
    const int NW = 2048 * 512;
    const int total = 3 * NW + 512 * 512 + 512 * 1024;
    int i = blockIdx.x * blockDim.x + threadIdx.x;
    int st = gridDim.x * blockDim.x;
    for (; i < total; i += st) {
        if (i < NW) {
            int n = i >> 9, k = i & 511;
            Wenc[i] = (f16)encWhh[rowp(n) * 512 + k];
        } else if (i < 2 * NW) {
            int j = i - NW; int n = j >> 9, k = j & 511;
            Wdih[j] = (f16)decWih[rowp(n) * 1024 + 512 + k];   // ht part of concat
        } else if (i < 3 * NW) {
            int j = i - 2 * NW; int n = j >> 9, k = j & 511;
            Wdhh[j] = (f16)decWhh[rowp(n) * 512 + k];
        } else if (i < 3 * NW + 512 * 512) {
            int j = i - 3 * NW;
            T2l[j] = (f16)ht2tan[j];
        } else {
            int j = i - 3 * NW - 512 * 512;
            CT2l[j] = (f16)ct2ht[j];
        }
    }
}

// W_final f32 -> f16 (runs AFTER scan; writes into the retired eg buffer).
__global__ void convert_wfinal(const float* __restrict__ Wf, f16* __restrict__ Wh) {
    const int total = 32000 * 512;
    int i = blockIdx.x * blockDim.x + threadIdx.x;
    int st = gridDim.x * blockDim.x;
    for (; i < total; i += st) Wh[i] = (f16)Wf[i];
}

// ---------------------------------------------------------------------------
// 64x64-tile f32 GEMM, gathered A rows, bias, scan-layout output (dg only):
// value for (row r = t*32+B, permuted col n) stored at
// [t][chain=B>>3][wg=n>>5][c=n&31][bb=B&7].
// ---------------------------------------------------------------------------
template <typename OutT>
__global__ __launch_bounds__(256) void gemm_gather(
    const float* __restrict__ emb, const int* __restrict__ idx,
    const float* __restrict__ W, int ldw,
    const float* __restrict__ bias, OutT* __restrict__ out) {
    __shared__ float As[16][65];
    __shared__ float Bs[16][65];
    const int tid = threadIdx.x;
    const int n0 = blockIdx.x * 64;
    const int r0 = blockIdx.y * 64;
    const int tx = tid & 15, ty = tid >> 4;
    const int lk = tid & 3,  lr = tid >> 2;
    const float* arow = emb + (size_t)idx[r0 + lr] * 512 + lk * 4;
    const float* brow = W + (size_t)rowp(n0 + lr) * ldw + lk * 4;
    float acc[4][4] = {};
    for (int k0 = 0; k0 < 512; k0 += 16) {
        float4 av = *(const float4*)(arow + k0);
        float4 bv = *(const float4*)(brow + k0);
        __syncthreads();
        As[lk * 4 + 0][lr] = av.x; As[lk * 4 + 1][lr] = av.y;
        As[lk * 4 + 2][lr] = av.z; As[lk * 4 + 3][lr] = av.w;
        Bs[lk * 4 + 0][lr] = bv.x; Bs[lk * 4 + 1][lr] = bv.y;
        Bs[lk * 4 + 2][lr] = bv.z; Bs[lk * 4 + 3][lr] = bv.w;
        __syncthreads();
#pragma unroll
        for (int k = 0; k < 16; k++) {
            float a4[4], b4[4];
#pragma unroll
            for (int i = 0; i < 4; i++) a4[i] = As[k][ty * 4 + i];
#pragma unroll
            for (int j = 0; j < 4; j++) b4[j] = Bs[k][tx * 4 + j];
#pragma unroll
            for (int i = 0; i < 4; i++)
#pragma unroll
                for (int j = 0; j < 4; j++) acc[i][j] = fmaf(a4[i], b4[j], acc[i][j]);
        }
    }
#pragma unroll
    for (int j = 0; j < 4; j++) {
        int n = n0 + tx * 4 + j;
        float bv2 = bias[rowp(n)];
#pragma unroll
        for (int i = 0; i < 4; i++) {
            int r = r0 + ty * 4 + i;
            int t = r >> 5, B = r & 31;
            size_t addr = ((((size_t)t * 4 + (B >> 3)) * 64 + (n >> 5)) * 32
                           + (n & 31)) * 8 + (B & 7);
            out[addr] = (OutT)(acc[i][j] + bv2);
        }
    }
}

// ---------------------------------------------------------------------------
// MFMA f16 GEMM for eg: out(r,n) = emb[idx[r]] . encWih[rowp(n)] + b[rowp(n)],
// stored f16 in scan layout.  64x64 tile, 4 waves, 16x16x32 MFMA.
// D-fragment: col = lane&15 (n), row = (lane>>4)*4 + reg (r).
// ---------------------------------------------------------------------------
__global__ __launch_bounds__(256) void gemm_eg_mfma(
    const float* __restrict__ emb, const int* __restrict__ idx,
    const float* __restrict__ W, const float* __restrict__ bias,
    f16* __restrict__ out) {
    __shared__ __align__(16) f16 Af[64][40];
    __shared__ __align__(16) f16 Bf[64][40];
    const int tid = threadIdx.x;
    const int n0 = blockIdx.x * 64;
    const int r0 = blockIdx.y * 64;
    const int srow = tid >> 2, sseg = tid & 3;
    const float* arow = emb + (size_t)idx[r0 + srow] * 512 + sseg * 8;
    const float* brow = W + (size_t)rowp(n0 + srow) * 512 + sseg * 8;
    const int w = tid >> 6, l = tid & 63;
    const int lr = l & 15, lk = l >> 4;
    f32x4v acc[4] = {};
    for (int k0 = 0; k0 < 512; k0 += 32) {
        float4 a0 = *(const float4*)(arow + k0);
        float4 a1 = *(const float4*)(arow + k0 + 4);
        float4 b0 = *(const float4*)(brow + k0);
        float4 b1 = *(const float4*)(brow + k0 + 4);
        __syncthreads();                          // prev iter frag reads done
        f16x8v av, bv;
        av[0]=(f16)a0.x; av[1]=(f16)a0.y; av[2]=(f16)a0.z; av[3]=(f16)a0.w;
        av[4]=(f16)a1.x; av[5]=(f16)a1.y; av[6]=(f16)a1.z; av[7]=(f16)a1.w;
        bv[0]=(f16)b0.x; bv[1]=(f16)b0.y; bv[2]=(f16)b0.z; bv[3]=(f16)b0.w;
        bv[4]=(f16)b1.x; bv[5]=(f16)b1.y; bv[6]=(f16)b1.z; bv[7]=(f16)b1.w;
        *(f16x8v*)&Af[srow][sseg * 8] = av;
        *(f16x8v*)&Bf[srow][sseg * 8] = bv;
        __syncthreads();
        f16x8v af = *(const f16x8v*)&Af[w * 16 + lr][lk * 8];
#pragma unroll
        for (int j = 0; j < 4; j++) {
            f16x8v bf = *(const f16x8v*)&Bf[j * 16 + lr][lk * 8];
            acc[j] = __builtin_amdgcn_mfma_f32_16x16x32_f16(af, bf, acc[j], 0, 0, 0);
        }
    }
    const int rq = r0 + w * 16 + lk * 4;          // quad base row (4-aligned)
    const int t = rq >> 5;
    const int B = rq & 31;                        // quad stays in one octet
#pragma unroll
    for (int j = 0; j < 4; j++) {
        int n = n0 + j * 16 + lr;
        float bb = bias[rowp(n)];
        f16x4v pk;
#pragma unroll
        for (int r = 0; r < 4; r++) pk[r] = (f16)(acc[j][r] + bb);
        size_t addr = ((((size_t)t * 4 + (B >> 3)) * 64 + (n >> 5)) * 32
                       + (n & 31)) * 8 + (B & 7);
        *(f16x4v*)(out + addr) = pk;              // 8B packed store
    }
}

// ---------------------------------------------------------------------------
// MFMA f16 projection + fused exp-sum / target-logit extraction.
// A = dout f16 [2048][512]; B = W_final f16 [32000][512].
// ---------------------------------------------------------------------------
__global__ __launch_bounds__(256) void proj_lse_mfma(
    const f16* __restrict__ A, const f16* __restrict__ Wh,
    const int* __restrict__ target,
    float* __restrict__ se, float* __restrict__ tl) {
    __shared__ __align__(16) f16 Af[64][40];
    __shared__ __align__(16) f16 Bf[64][40];
    const int tid = threadIdx.x;
    const int v0 = blockIdx.x * 64;
    const int r0 = blockIdx.y * 64;
    const int srow = tid >> 2, sseg = tid & 3;
    const f16* arow = A + (size_t)(r0 + srow) * 512 + sseg * 8;
    const f16* brow = Wh + (size_t)(v0 + srow) * 512 + sseg * 8;
    const int w = tid >> 6, l = tid & 63;
    const int lr = l & 15, lk = l >> 4;
    f32x4v acc[4] = {};
    for (int k0 = 0; k0 < 512; k0 += 32) {
        f16x8v av = *(const f16x8v*)(arow + k0);
        f16x8v bv = *(const f16x8v*)(brow + k0);
        __syncthreads();
        *(f16x8v*)&Af[srow][sseg * 8] = av;
        *(f16x8v*)&Bf[srow][sseg * 8] = bv;
        __syncthreads();
        f16x8v af = *(const f16x8v*)&Af[w * 16 + lr][lk * 8];
#pragma unroll
        for (int j = 0; j < 4; j++) {
            f16x8v bf = *(const f16x8v*)&Bf[j * 16 + lr][lk * 8];
            acc[j] = __builtin_amdgcn_mfma_f32_16x16x32_f16(af, bf, acc[j], 0, 0, 0);
        }
    }
#pragma unroll
    for (int r = 0; r < 4; r++) {
        int rg = r0 + w * 16 + lk * 4 + r;
        int tg = target[32 + rg];
        float es = 0.0f;
#pragma unroll
        for (int j = 0; j < 4; j++) {
            int n = v0 + j * 16 + lr;
            float lv = acc[j][r];
            if (n == tg) atomicAdd(&tl[rg], lv);
            es += __expf(lv);
        }
#pragma unroll
        for (int m = 1; m < 16; m <<= 1) es += __shfl_xor(es, m);
        if (lr == 0) atomicAdd(&se[rg], es);
    }
}

// ---------------------------------------------------------------------------
// Persistent scan (round-7 sync, verified): 256 WGs x 512 threads = 4 chains
// x 64 WGs.  All cross-WG handoffs are sentinel-polled data loads.
// Round-11 change: per-thread weight slices hoisted to VGPRs (encoder Wenc,
// then reloaded with Wdih for decoder stage A).
// ---------------------------------------------------------------------------
__global__ __launch_bounds__(512, 2) void scan_kernel(
    const f16* __restrict__ eg,      // [1024][CH][64][32][8]
    const float* __restrict__ dg,    // [64][CH][64][32][8]
    const f16* __restrict__ Wenc,    // [2048][512] rows in permuted col order
    const f16* __restrict__ Wdih,    // [2048][512]
    const f16* __restrict__ Wdhh,    // [2048][512]
    const f16* __restrict__ T2l,     // [512][512]
    const f16* __restrict__ CT2l,    // [512][1024]
    const float* __restrict__ wpt,   // [512]
    f16* __restrict__ h_hist,        // [CH][1089][8][512] slot0 zero, rest sentinel
    f16* __restrict__ q_hist,        // [CH][65][8][512]  slot0 zero, rest sentinel
    f16* __restrict__ ctb,           // [64][CH][8][512]  sentinel-filled
    float* __restrict__ ppart,       // [64][CH][8][64]   sentinel-filled
    f16* __restrict__ dout) {        // [2048][512] f16
    const int bid = blockIdx.x;
    const int chain = bid >> 6;
    const int wg = bid & 63;
    const int tid = threadIdx.x;

    f16* hc = h_hist + (size_t)chain * 1089 * 4096;
    f16* qc = q_hist + (size_t)chain * 65 * 4096;

    __shared__ __align__(16) f16  Ws[32 * 520];    // 33280 B encoder weights
    __shared__ __align__(16) f16  hst[8 * 520];    //  8320 B h[t] staging
    __shared__ __align__(16) f16  qst[8 * 520];    //  prev ht staging (decoder)
    __shared__ __align__(16) f16  yst[8 * 520];    //  yt staging (decoder)
    __shared__ __align__(16) f16  ctst[8 * 520];   //  ct staging (decoder)
    __shared__ float part[512];
    __shared__ float zbS[64];
    __shared__ float spart[64 * 9];
    __shared__ float scS[64];
    __shared__ float atwS[64];
    __shared__ float ptS[1];

    const int c  = (tid >> 3) & 31;   // gate col (local)
    const int bq = tid & 7;           // batch (local)
    const int kh = tid >> 8;          // k half
    const int sb = tid >> 6, sj = tid & 63;   // staging: batch, 16B chunk (full row)
    const int au = tid & 7, ab = tid >> 3;    // activation: uu, bq (tid<64)

    // stage encoder weight slice (32 rows x 512) into LDS, 520-f16 padded rows
    {
        int r = tid >> 4, seg = tid & 15;
        const float4* s4 = (const float4*)(Wenc + (size_t)(wg * 32 + r) * 512) + seg * 4;
        float4 a0 = s4[0], a1 = s4[1], a2 = s4[2], a3 = s4[3];
        float4* d4 = (float4*)(Ws + r * 520) + seg * 4;
        d4[0] = a0; d4[1] = a1; d4[2] = a2; d4[3] = a3;
    }
    __syncthreads();

    // hoist this thread's encoder weight slice (256 f16 = 128 VGPRs) to regs
    V8 wreg[32];
    {
        const f16* Wr = Ws + c * 520 + kh * 256;
#pragma unroll
        for (int k8 = 0; k8 < 32; k8++) wreg[k8].f4 = *(const float4*)(Wr + k8 * 8);
    }

    float creg = 0.0f;                // cell state (tid<64)

    float egv = 0.0f;
    if (kh == 0)
        egv = (float)eg[(size_t)chain * 16384 + wg * 256 + c * 8 + bq];

    // ---------------- encoder: 1024 steps, ZERO barriers ----------------
    for (int t = 0; t < 1024; t++) {
        {   // poll-stage h[t] (8KB) -> LDS; chunk (sb,sj) produced by WG sj
            i32x4 v = poll16(hc + (size_t)t * 4096 + sb * 512 + sj * 8);
            *((i32x4*)(hst + sb * 520) + sj) = v;
        }
        float egn = 0.0f;
        if (kh == 0 && t < 1023)   // prefetch next step's gate (in flight thru dot)
            egn = (float)eg[((size_t)(t + 1) * 4 + chain) * 16384 + wg * 256 + c * 8 + bq];
        __syncthreads();
        {   // dot: col c, batch bq, k-half kh; weights from VGPRs
            const f16* hr = hst + bq * 520 + kh * 256;
            float a0 = (kh == 0) ? egv : 0.0f;
#pragma unroll
            for (int k8 = 0; k8 < 32; k8++) {
                V8 xv;
                xv.f4 = *(const float4*)(hr + k8 * 8);
#pragma unroll
                for (int q = 0; q < 4; q++) a0 = dot2f(wreg[k8].p[q], xv.p[q], a0);
            }
            part[tid] = a0;
        }
        egv = egn;
        __syncthreads();
        if (tid < 64) {
            float gi = part[(au)      * 8 + ab] + part[256 + (au)      * 8 + ab];
            float gf = part[(8 + au)  * 8 + ab] + part[256 + (8 + au)  * 8 + ab];
            float gg = part[(16 + au) * 8 + ab] + part[256 + (16 + au) * 8 + ab];
            float go = part[(24 + au) * 8 + ab] + part[256 + (24 + au) * 8 + ab];
            float cc = sigf(gf) * creg + sigf(gi) * tanh_f(gg);
            float hh = sigf(go) * tanh_f(cc);
            creg = cc;
            // fire-and-forget: consumers poll the data itself
            st_wt_b16(hc + (size_t)(t + 1) * 4096 + ab * 512 + wg * 8 + au, (f16)hh);
        }
        // no barrier: next iteration's poll gates on h[t+1] arrival
    }

    // ---------------- decoder: 64 steps, ZERO barriers ----------------
    // re-purpose the weight registers with the Wdih slice (loop-invariant)
    {
        const f16* W1 = Wdih + (size_t)(wg * 32 + c) * 512 + kh * 256;
#pragma unroll
        for (int k8 = 0; k8 < 32; k8++) wreg[k8].f4 = *(const float4*)(W1 + k8 * 8);
    }
    // pre-stage yst = hc[1024] (encoder final h; doubles as hsrc for t=0)
    {
        i32x4 v = poll16(hc + (size_t)1024 * 4096 + sb * 512 + sj * 8);
        *((i32x4*)(yst + sb * 520) + sj) = v;
    }

    for (int t = 0; t < 64; t++) {
        f16* ydst = hc + (size_t)(1025 + t) * 4096;       // yt slot

        // ---- stage A: gates = dg + Wih_h.ht + Whh.h; ht from qst, h from yst ----
        {   // poll-stage qc[t] (8KB) -> qst, full row coverage
            i32x4 v = poll16(qc + (size_t)t * 4096 + sb * 512 + sj * 8);
            *((i32x4*)(qst + sb * 520) + sj) = v;
        }
        __syncthreads();
        {
            float dgv = (kh == 0)
                ? dg[((size_t)t * 4 + chain) * 16384 + wg * 256 + c * 8 + bq] : 0.0f;
            const f16* W2 = Wdhh + (size_t)(wg * 32 + c) * 512 + kh * 256;
            const f16* q0 = qst + bq * 520 + kh * 256;
            const f16* h0 = yst + bq * 520 + kh * 256;
            float a0 = dgv;
#pragma unroll
            for (int k8 = 0; k8 < 32; k8++) {
                V8 w2, x0, y0;
                x0.f4 = *(const float4*)(q0 + k8 * 8);
                w2.f4 = *(const float4*)(W2 + k8 * 8);
                y0.f4 = *(const float4*)(h0 + k8 * 8);
#pragma unroll
                for (int q = 0; q < 4; q++) {
                    a0 = dot2f(wreg[k8].p[q], x0.p[q], a0);
                    a0 = dot2f(w2.p[q], y0.p[q], a0);
                }
            }
            part[tid] = a0;
        }
        __syncthreads();
        if (tid < 64) {
            float gi = part[(au)      * 8 + ab] + part[256 + (au)      * 8 + ab];
            float gf = part[(8 + au)  * 8 + ab] + part[256 + (8 + au)  * 8 + ab];
            float gg = part[(16 + au) * 8 + ab] + part[256 + (16 + au) * 8 + ab];
            float go = part[(24 + au) * 8 + ab] + part[256 + (24 + au) * 8 + ab];
            float cc = sigf(gf) * creg + sigf(gi) * tanh_f(gg);
            float hh = sigf(go) * tanh_f(cc);
            creg = cc;
            st_wt_b16(ydst + ab * 512 + wg * 8 + au, (f16)hh);
        }

        // ---- stage B: poll-stage yt -> yst; z = tanh(yt @ W_ht2tan.T); pt partial ----
        {
            i32x4 v = poll16(ydst + sb * 512 + sj * 8);
            *((i32x4*)(yst + sb * 520) + sj) = v;
        }
        __syncthreads();
        {
            int kq = tid >> 6, zu = (tid >> 3) & 7, zq = tid & 7;
            const f16* Tr = T2l + (size_t)(wg * 8 + zu) * 512 + kq * 64;
            const f16* yr = yst + zq * 520 + kq * 64;
            float s = 0.0f;
#pragma unroll
            for (int k = 0; k < 64; k += 8) {
                V8 aa, bb;
                aa.f4 = *(const float4*)(Tr + k);
                bb.f4 = *(const float4*)(yr + k);
#pragma unroll
                for (int q = 0; q < 4; q++) s = dot2f(aa.p[q], bb.p[q], s);
            }
            part[tid] = s;
        }
        __syncthreads();
        if (tid < 64) {
            float z = 0.0f;
#pragma unroll
            for (int kq = 0; kq < 8; kq++) z += part[kq * 64 + tid];
            zbS[tid] = tanh_f(z);             // zbS[zu*8 + zq]
        }
        __syncthreads();
        if (tid < 8) {
            float pp = 0.0f;
#pragma unroll
            for (int u2 = 0; u2 < 8; u2++) pp += zbS[u2 * 8 + tid] * wpt[wg * 8 + u2];
            st_wt_f32(&ppart[(((size_t)t * 4 + chain) * 8 + tid) * 64 + wg], pp);
        }

        // ---- stage C: local attention (WG wg<8 owns chain-batch wg) ----
        if (wg < 8) {
            const int bb = wg;
            if (tid < 64) {
                const float* pa = ppart + (((size_t)t * 4 + chain) * 8 + bb) * 64 + tid;
                unsigned bits = ld_bypass_u32(pa);
                while (bits == 0xFFFFFFFFu) bits = ld_bypass_u32(pa);
                union { unsigned u; float f; } cv; cv.u = bits;
                float v = cv.f;
#pragma unroll
                for (int off = 32; off > 0; off >>= 1) v += __shfl_down(v, off);
                if (tid == 0) ptS[0] = v;
            }
            __syncthreads();
            float pt = sigf(ptS[0]);
            float center = 1024.0f * pt;
            int ci = (int)floorf(center);
            int left = max(0, ci - 32);
            int right = min(1024, ci + 32);
            int win = right - left;
            int p = tid >> 3, seg = tid & 7;
            if (p < win) {
                const f16* yr = yst + bb * 520 + seg * 64;
                const f16* er = hc + (size_t)(left + p + 1) * 4096 + bb * 512 + seg * 64;
                float s = 0.0f;
#pragma unroll
                for (int k = 0; k < 64; k += 8) {
                    V8 aa, bbv;
                    aa.f4  = *(const float4*)(yr + k);
                    bbv.f4 = *(const float4*)(er + k);
#pragma unroll
                    for (int q = 0; q < 4; q++) s = dot2f(aa.p[q], bbv.p[q], s);
                }
                spart[p * 9 + seg] = s;
            }
            __syncthreads();
            if (tid < 64) {
                float s = -1e30f;
                if (tid < win) {
                    s = 0.0f;
#pragma unroll
                    for (int x = 0; x < 8; x++) s += spart[tid * 9 + x];
                }
                scS[tid] = s;
            }
            __syncthreads();
            float mx = -1e30f;
            for (int q2 = 0; q2 < 64; q2++) mx = fmaxf(mx, scS[q2]);
            float sum = 0.0f;
            for (int q2 = 0; q2 < 64; q2++) sum += __expf(scS[q2] - mx);
            if (tid < 64) {
                float sp = (float)(left + tid) - center;
                float gs = __expf(-(sp * sp) * (1.0f / 512.0f));
                atwS[tid] = (tid < win) ? (__expf(scS[tid] - mx) / sum) * gs : 0.0f;
            }
            __syncthreads();
            {
                int j = tid;   // 0..511
                float a = 0.0f;
                const f16* ebase = hc + (size_t)(left + 1) * 4096 + bb * 512 + j;
                for (int p2 = 0; p2 < win; p2++)
                    a += atwS[p2] * (float)ebase[(size_t)p2 * 4096];
                st_wt_b16(ctb + ((((size_t)t * 4 + chain) * 8 + bb) * 512) + j, (f16)a);
            }
        }

        // ---- stage D: poll-stage ct -> ctst; ht_new = tanh([ct, yt] @ W_ct2ht.T) ----
        {
            i32x4 v = poll16(ctb + (((size_t)t * 4 + chain) * 8 + sb) * 512 + sj * 8);
            *((i32x4*)(ctst + sb * 520) + sj) = v;
        }
        __syncthreads();
        {
            int kq = tid >> 6, du = (tid >> 3) & 7, dq = tid & 7;
            const f16* Cr = CT2l + (size_t)(wg * 8 + du) * 1024 + kq * 128;
            const f16* xr = (kq < 4)
                ? (ctst + dq * 520 + kq * 128)
                : (yst + dq * 520 + (kq - 4) * 128);
            float s = 0.0f;
#pragma unroll 4
            for (int k = 0; k < 128; k += 8) {
                V8 aa, bb;
                aa.f4 = *(const float4*)(Cr + k);
                bb.f4 = *(const float4*)(xr + k);
#pragma unroll
                for (int q = 0; q < 4; q++) s = dot2f(aa.p[q], bb.p[q], s);
            }
            part[tid] = s;
        }
        __syncthreads();
        if (tid < 64) {
            float s = 0.0f;
#pragma unroll
            for (int kq = 0; kq < 8; kq++) s += part[kq * 64 + tid];
            float hv = tanh_f(s);
            int du = tid >> 3, dq = tid & 7;
            st_wt_b16(qc + (size_t)(t + 1) * 4096 + dq * 512 + wg * 8 + du, (f16)hv);
            dout[((size_t)t * 32 + chain * 8 + dq) * 512 + wg * 8 + du] = (f16)hv;
        }
        // no end barrier: stage A(t+1) polls qc[t+1]
    }
}

__global__ void finalize_out(const float* __restrict__ se, const float* __restrict__ tl,
                             const int* __restrict__ target, float* __restrict__ out) {
    int b = threadIdx.x;
    if (b >= 32) return;
    float s = 0.0f;
    for (int t = 0; t < 64; t++) {
        int r = t * 32 + b;
        int tg = target[(t + 1) * 32 + b];
        if (tg != 0) s += tl[r] - logf(se[r]);
    }
    out[b] = s;
}

// ---------------------------------------------------------------------------
extern "C" void kernel_launch(void* const* d_in, const int* in_sizes, int n_in,
                              void* d_out, int out_size, void* d_ws, size_t ws_size,
                              hipStream_t stream) {
    const int*   source   = (const int*)  d_in[0];
    const int*   target   = (const int*)  d_in[1];
    const float* src_emb  = (const float*)d_in[2];
    const float* tar_emb  = (const float*)d_in[3];
    const float* enc_Wih  = (const float*)d_in[4];
    const float* enc_Whh  = (const float*)d_in[5];
    const float* enc_b    = (const float*)d_in[6];
    const float* dec_Wih  = (const float*)d_in[7];
    const float* dec_Whh  = (const float*)d_in[8];
    const float* dec_b    = (const float*)d_in[9];
    const float* W_ht2tan = (const float*)d_in[10];
    const float* W_tan2pt = (const float*)d_in[11];
    const float* W_ct2ht  = (const float*)d_in[12];
    const float* W_final  = (const float*)d_in[13];
    float* out = (float*)d_out;

    char* ws = (char*)d_ws;
    size_t off = 0;
    auto alloc = [&](size_t bytes) -> char* {
        char* p = ws + off;
        off = (off + bytes + 255) & ~(size_t)255;
        return p;
    };
    f16*   h_hist = (f16*)  alloc((size_t)CH * 1089 * 4096 * 2);  // 35.7 MB
    f16*   q_hist = (f16*)  alloc((size_t)CH * 65 * 4096 * 2);
    f16*   ctb    = (f16*)  alloc((size_t)64 * CH * 8 * 512 * 2);
    float* ppart  = (float*)alloc((size_t)64 * CH * 8 * 64 * 4);
    float* se     = (float*)alloc((size_t)2048 * 4);
    float* tl     = (float*)alloc((size_t)2048 * 4);
    f16*   eg     = (f16*)  alloc((size_t)32768 * 2048 * 2);      // 128 MB
    float* dg     = (float*)alloc((size_t)2048 * 2048 * 4);       // 16 MB
    f16*   Wenc   = (f16*)  alloc((size_t)2048 * 512 * 2);
    f16*   Wdih   = (f16*)  alloc((size_t)2048 * 512 * 2);
    f16*   Wdhh   = (f16*)  alloc((size_t)2048 * 512 * 2);
    f16*   T2l    = (f16*)  alloc((size_t)512 * 512 * 2);
    f16*   CT2l   = (f16*)  alloc((size_t)512 * 1024 * 2);
    f16*   dout   = (f16*)  alloc((size_t)2048 * 512 * 2);
    f16*   Wf16   = eg;     // reuse: eg is dead after scan; 32000*512*2 = 33MB <= 128MB

    fill_sentinel<<<2048, 256, 0, stream>>>((i32x4*)h_hist, (i32x4*)q_hist,
                                            (i32x4*)ctb, (i32x4*)ppart, se, tl);
    convert_weights<<<2048, 256, 0, stream>>>(enc_Whh, dec_Wih, dec_Whh, W_ht2tan, W_ct2ht,
                                              Wenc, Wdih, Wdhh, T2l, CT2l);
    gemm_eg_mfma<<<dim3(32, 512), 256, 0, stream>>>(src_emb, source, enc_Wih, enc_b, eg);
    gemm_gather<float><<<dim3(32, 32), 256, 0, stream>>>(tar_emb, target, dec_Wih, 1024,
                                                         dec_b, dg);
    scan_kernel<<<CH * WPC, 512, 0, stream>>>(eg, dg, Wenc, Wdih, Wdhh, T2l, CT2l,
                                              W_tan2pt, h_hist, q_hist, ctb, ppart,
                                              dout);
    convert_wfinal<<<2048, 256, 0, stream>>>(W_final, Wf16);
    proj_lse_mfma<<<dim3(500, 32), 256, 0, stream>>>(dout, Wf16, target, se, tl);
    finalize_out<<<1, 64, 0, stream>>>(se, tl, target, out);
}

// Round 8
// 5384.354 us; speedup vs baseline: 4.1551x; 1.1016x over previous
//
#include <hip/hip_runtime.h>
#include <stdint.h>
#include <math.h>

// ---------------------------------------------------------------------------
// NMT seq2seq: encoder LSTM (S=1024) -> decoder LSTM + local attention (T=64)
// -> fused projection/log-softmax NLL.
//
// Round 12: encoder gate dot moved to MFMA on wave 0.  Per WG per step the
// gate GEMM is D[32 cols][8 batches] = Ws(32x512) . h(8x512)^T = 2 M-tiles x
// 16 K-tiles of mfma_f32_16x16x32_f16 (operand mapping identical to the
// verified gemm_eg_mfma).  Weight A-fragments are STATIC in 128 VGPRs for
// all 1024 steps.  h is staged into a DOUBLE-BUFFERED hb[2][16][520] (rows
// 8..15 zero = N padding), giving ONE barrier per encoder step: waves 1-7
// return to polling t+1 into the other buffer while wave 0 does MFMA ->
// part -> activation -> store.  Race-free: staging of t+2 into buf[t&1] is
// gated by barrier(t+1), which wave 0 reaches only after its buf[t&1] reads.
// eg enters via a per-lane 4-value prefetch added at activation (same
// algebra as the old a0=egv dot seed).  Decoder verbatim from round 11
// (verified), with its Wdih reg slice reloaded after the encoder.
// Sentinel sync protocol (round 7, verified) untouched.
// ---------------------------------------------------------------------------

typedef _Float16 f16;
typedef _Float16 f16x2 __attribute__((ext_vector_type(2)));
typedef _Float16 f16x4v __attribute__((ext_vector_type(4)));
typedef _Float16 f16x8v __attribute__((ext_vector_type(8)));
typedef float    f32x4v __attribute__((ext_vector_type(4)));
typedef int i32x4 __attribute__((ext_vector_type(4)));

union V8 { f16x2 p[4]; float4 f4; };

#define CH  4            // independent batch chains
#define WPC 64           // workgroups per chain

__device__ __forceinline__ float dot2f(f16x2 a, f16x2 b, float c) {
#if __has_builtin(__builtin_amdgcn_fdot2)
    return __builtin_amdgcn_fdot2(a, b, c, false);
#else
    return c + (float)a[0] * (float)b[0] + (float)a[1] * (float)b[1];
#endif
}

__device__ __forceinline__ float sigf(float x) { return 1.0f / (1.0f + __expf(-x)); }

__device__ __forceinline__ float tanh_f(float x) {
    float ax = fminf(fabsf(x), 12.0f);
    float e  = __expf(2.0f * ax);
    float r  = (e - 1.0f) / (e + 1.0f);
    return copysignf(r, x);
}

// write-through stores: bypass L1/L2, land at coherence point (MALL)
__device__ __forceinline__ void st_wt_b16(f16* p, f16 v) {
    union { f16 h; uint16_t u; } cv; cv.h = v;
    uint32_t d = cv.u;
    asm volatile("global_store_short %0, %1, off sc0 sc1" :: "v"(p), "v"(d) : "memory");
}
__device__ __forceinline__ void st_wt_f32(float* p, float v) {
    union { float f; int i; } cv; cv.f = v;
    asm volatile("global_store_dword %0, %1, off sc0 sc1" :: "v"(p), "v"(cv.i) : "memory");
}
__device__ __forceinline__ void st_wt_b128(i32x4* p, i32x4 v) {
    asm volatile("global_store_dwordx4 %0, %1, off sc0 sc1" :: "v"(p), "v"(v) : "memory");
}
// bypass loads: straight from MALL, never L1/L2 (so polling can't see stale)
__device__ __forceinline__ i32x4 ld_bypass4(const void* p) {
    i32x4 v;
    asm volatile("global_load_dwordx4 %0, %1, off sc0 sc1\n\ts_waitcnt vmcnt(0)"
                 : "=v"(v) : "v"(p) : "memory");
    return v;
}
__device__ __forceinline__ unsigned ld_bypass_u32(const void* p) {
    unsigned v;
    asm volatile("global_load_dword %0, %1, off sc0 sc1\n\ts_waitcnt vmcnt(0)"
                 : "=v"(v) : "v"(p) : "memory");
    return v;
}

// 16B chunk of 8 f16s is valid iff no half equals the sentinel 0xFFFF (-NaN).
// Real values are finite (|h|<1, |ct|<=64), so 0xFFFF is unreachable.
__device__ __forceinline__ bool chunk_ok(i32x4 v) {
    unsigned a = ~(unsigned)v[0], b = ~(unsigned)v[1];
    unsigned c = ~(unsigned)v[2], d = ~(unsigned)v[3];
    unsigned ok = (unsigned)((a & 0xFFFFu) != 0u) & (unsigned)((a >> 16) != 0u)
                & (unsigned)((b & 0xFFFFu) != 0u) & (unsigned)((b >> 16) != 0u)
                & (unsigned)((c & 0xFFFFu) != 0u) & (unsigned)((c >> 16) != 0u)
                & (unsigned)((d & 0xFFFFu) != 0u) & (unsigned)((d >> 16) != 0u);
    return ok != 0u;
}

__device__ __forceinline__ i32x4 poll16(const f16* gp) {
    i32x4 v = ld_bypass4(gp);
    while (!chunk_ok(v)) v = ld_bypass4(gp);
    return v;
}

// gate-column permutation: global permuted col n (0..2047) -> original (4H) row.
// n = wg*32 + g*8 + uu  ->  g*512 + wg*8 + uu   (WG wg owns h-units wg*8..wg*8+8)
__device__ __forceinline__ int rowp(int n) {
    return (((n & 31) >> 3) * 512) + ((n >> 5) * 8) + (n & 7);
}

// ---------------------------------------------------------------------------
// Sentinel fill (write-through!).  h_hist/q_hist slot 0 of each chain = 0.0
// (real initial state); everything else = 0xFFFF per f16 / 0xFFFFFFFF per f32.
// ---------------------------------------------------------------------------
__global__ void fill_sentinel(i32x4* h, i32x4* q, i32x4* c, i32x4* p,
                              float* se, float* tl) {
    const size_t NH = (size_t)CH * 1089 * 512;   // h_hist in int4 units
    const size_t NQ = (size_t)CH * 65 * 512;     // q_hist
    const size_t NC = (size_t)64 * CH * 8 * 64;  // ctb
    const size_t NP = (size_t)64 * CH * 8 * 16;  // ppart (f32)
    const size_t total = NH + NQ + NC + NP;
    const i32x4 S = {-1, -1, -1, -1};
    const i32x4 Z = {0, 0, 0, 0};
    size_t stp = (size_t)gridDim.x * blockDim.x;
    for (size_t i = (size_t)blockIdx.x * blockDim.x + threadIdx.x; i < total; i += stp) {
        if (i < NH) {
            size_t r = i % (size_t)(1089 * 512);
            st_wt_b128(h + i, (r < 512) ? Z : S);
        } else if (i < NH + NQ) {
            size_t j = i - NH;
            size_t r = j % (size_t)(65 * 512);
            st_wt_b128(q + j, (r < 512) ? Z : S);
        } else if (i < NH + NQ + NC) {
            st_wt_b128(c + (i - NH - NQ), S);
        } else {
            st_wt_b128(p + (i - NH - NQ - NC), S);
        }
    }
    size_t g = (size_t)blockIdx.x * blockDim.x + threadIdx.x;
    if (g < 2048) { se[g] = 0.0f; tl[g] = 0.0f; }
}

// Convert / permute weights to f16 scan layouts.
__global__ void convert_weights(const float* __restrict__ encWhh,
                                const float* __restrict__ decWih,
                                const float* __restrict__ decWhh,
                                const float* __restrict__ ht2tan,
                                const float* __restrict__ ct2ht,
                                f16* __restrict__ Wenc, f16* __restrict__ Wdih,
                                f16* __restrict__ Wdhh, f16* __restrict__ T2l,
                                f16* __restrict__ CT2l) {
    const int NW = 2048 * 512;
    const int total = 3 * NW + 512 * 512 + 512 * 1024;
    int i = blockIdx.x * blockDim.x + threadIdx.x;
    int st = gridDim.x * blockDim.x;
    for (; i < total; i += st) {
        if (i < NW) {
            int n = i >> 9, k = i & 511;
            Wenc[i] = (f16)encWhh[rowp(n) * 512 + k];
        } else if (i < 2 * NW) {
            int j = i - NW; int n = j >> 9, k = j & 511;
            Wdih[j] = (f16)decWih[rowp(n) * 1024 + 512 + k];   // ht part of concat
        } else if (i < 3 * NW) {
            int j = i - 2 * NW; int n = j >> 9, k = j & 511;
            Wdhh[j] = (f16)decWhh[rowp(n) * 512 + k];
        } else if (i < 3 * NW + 512 * 512) {
            int j = i - 3 * NW;
            T2l[j] = (f16)ht2tan[j];
        } else {
            int j = i - 3 * NW - 512 * 512;
            CT2l[j] = (f16)ct2ht[j];
        }
    }
}

// W_final f32 -> f16 (runs AFTER scan; writes into the retired eg buffer).
__global__ void convert_wfinal(const float* __restrict__ Wf, f16* __restrict__ Wh) {
    const int total = 32000 * 512;
    int i = blockIdx.x * blockDim.x + threadIdx.x;
    int st = gridDim.x * blockDim.x;
    for (; i < total; i += st) Wh[i] = (f16)Wf[i];
}

// ---------------------------------------------------------------------------
// 64x64-tile f32 GEMM, gathered A rows, bias, scan-layout output (dg only).
// ---------------------------------------------------------------------------
template <typename OutT>
__global__ __launch_bounds__(256) void gemm_gather(
    const float* __restrict__ emb, const int* __restrict__ idx,
    const float* __restrict__ W, int ldw,
    const float* __restrict__ bias, OutT* __restrict__ out) {
    __shared__ float As[16][65];
    __shared__ float Bs[16][65];
    const int tid = threadIdx.x;
    const int n0 = blockIdx.x * 64;
    const int r0 = blockIdx.y * 64;
    const int tx = tid & 15, ty = tid >> 4;
    const int lk = tid & 3,  lr = tid >> 2;
    const float* arow = emb + (size_t)idx[r0 + lr] * 512 + lk * 4;
    const float* brow = W + (size_t)rowp(n0 + lr) * ldw + lk * 4;
    float acc[4][4] = {};
    for (int k0 = 0; k0 < 512; k0 += 16) {
        float4 av = *(const float4*)(arow + k0);
        float4 bv = *(const float4*)(brow + k0);
        __syncthreads();
        As[lk * 4 + 0][lr] = av.x; As[lk * 4 + 1][lr] = av.y;
        As[lk * 4 + 2][lr] = av.z; As[lk * 4 + 3][lr] = av.w;
        Bs[lk * 4 + 0][lr] = bv.x; Bs[lk * 4 + 1][lr] = bv.y;
        Bs[lk * 4 + 2][lr] = bv.z; Bs[lk * 4 + 3][lr] = bv.w;
        __syncthreads();
#pragma unroll
        for (int k = 0; k < 16; k++) {
            float a4[4], b4[4];
#pragma unroll
            for (int i = 0; i < 4; i++) a4[i] = As[k][ty * 4 + i];
#pragma unroll
            for (int j = 0; j < 4; j++) b4[j] = Bs[k][tx * 4 + j];
#pragma unroll
            for (int i = 0; i < 4; i++)
#pragma unroll
                for (int j = 0; j < 4; j++) acc[i][j] = fmaf(a4[i], b4[j], acc[i][j]);
        }
    }
#pragma unroll
    for (int j = 0; j < 4; j++) {
        int n = n0 + tx * 4 + j;
        float bv2 = bias[rowp(n)];
#pragma unroll
        for (int i = 0; i < 4; i++) {
            int r = r0 + ty * 4 + i;
            int t = r >> 5, B = r & 31;
            size_t addr = ((((size_t)t * 4 + (B >> 3)) * 64 + (n >> 5)) * 32
                           + (n & 31)) * 8 + (B & 7);
            out[addr] = (OutT)(acc[i][j] + bv2);
        }
    }
}

// ---------------------------------------------------------------------------
// MFMA f16 GEMM for eg (verified round 10/11).
// ---------------------------------------------------------------------------
__global__ __launch_bounds__(256) void gemm_eg_mfma(
    const float* __restrict__ emb, const int* __restrict__ idx,
    const float* __restrict__ W, const float* __restrict__ bias,
    f16* __restrict__ out) {
    __shared__ __align__(16) f16 Af[64][40];
    __shared__ __align__(16) f16 Bf[64][40];
    const int tid = threadIdx.x;
    const int n0 = blockIdx.x * 64;
    const int r0 = blockIdx.y * 64;
    const int srow = tid >> 2, sseg = tid & 3;
    const float* arow = emb + (size_t)idx[r0 + srow] * 512 + sseg * 8;
    const float* brow = W + (size_t)rowp(n0 + srow) * 512 + sseg * 8;
    const int w = tid >> 6, l = tid & 63;
    const int lr = l & 15, lk = l >> 4;
    f32x4v acc[4] = {};
    for (int k0 = 0; k0 < 512; k0 += 32) {
        float4 a0 = *(const float4*)(arow + k0);
        float4 a1 = *(const float4*)(arow + k0 + 4);
        float4 b0 = *(const float4*)(brow + k0);
        float4 b1 = *(const float4*)(brow + k0 + 4);
        __syncthreads();                          // prev iter frag reads done
        f16x8v av, bv;
        av[0]=(f16)a0.x; av[1]=(f16)a0.y; av[2]=(f16)a0.z; av[3]=(f16)a0.w;
        av[4]=(f16)a1.x; av[5]=(f16)a1.y; av[6]=(f16)a1.z; av[7]=(f16)a1.w;
        bv[0]=(f16)b0.x; bv[1]=(f16)b0.y; bv[2]=(f16)b0.z; bv[3]=(f16)b0.w;
        bv[4]=(f16)b1.x; bv[5]=(f16)b1.y; bv[6]=(f16)b1.z; bv[7]=(f16)b1.w;
        *(f16x8v*)&Af[srow][sseg * 8] = av;
        *(f16x8v*)&Bf[srow][sseg * 8] = bv;
        __syncthreads();
        f16x8v af = *(const f16x8v*)&Af[w * 16 + lr][lk * 8];
#pragma unroll
        for (int j = 0; j < 4; j++) {
            f16x8v bf = *(const f16x8v*)&Bf[j * 16 + lr][lk * 8];
            acc[j] = __builtin_amdgcn_mfma_f32_16x16x32_f16(af, bf, acc[j], 0, 0, 0);
        }
    }
    const int rq = r0 + w * 16 + lk * 4;          // quad base row (4-aligned)
    const int t = rq >> 5;
    const int B = rq & 31;                        // quad stays in one octet
#pragma unroll
    for (int j = 0; j < 4; j++) {
        int n = n0 + j * 16 + lr;
        float bb = bias[rowp(n)];
        f16x4v pk;
#pragma unroll
        for (int r = 0; r < 4; r++) pk[r] = (f16)(acc[j][r] + bb);
        size_t addr = ((((size_t)t * 4 + (B >> 3)) * 64 + (n >> 5)) * 32
                       + (n & 31)) * 8 + (B & 7);
        *(f16x4v*)(out + addr) = pk;              // 8B packed store
    }
}

// ---------------------------------------------------------------------------
// MFMA f16 projection + fused exp-sum / target-logit extraction (verified).
// ---------------------------------------------------------------------------
__global__ __launch_bounds__(256) void proj_lse_mfma(
    const f16* __restrict__ A, const f16* __restrict__ Wh,
    const int* __restrict__ target,
    float* __restrict__ se, float* __restrict__ tl) {
    __shared__ __align__(16) f16 Af[64][40];
    __shared__ __align__(16) f16 Bf[64][40];
    const int tid = threadIdx.x;
    const int v0 = blockIdx.x * 64;
    const int r0 = blockIdx.y * 64;
    const int srow = tid >> 2, sseg = tid & 3;
    const f16* arow = A + (size_t)(r0 + srow) * 512 + sseg * 8;
    const f16* brow = Wh + (size_t)(v0 + srow) * 512 + sseg * 8;
    const int w = tid >> 6, l = tid & 63;
    const int lr = l & 15, lk = l >> 4;
    f32x4v acc[4] = {};
    for (int k0 = 0; k0 < 512; k0 += 32) {
        f16x8v av = *(const f16x8v*)(arow + k0);
        f16x8v bv = *(const f16x8v*)(brow + k0);
        __syncthreads();
        *(f16x8v*)&Af[srow][sseg * 8] = av;
        *(f16x8v*)&Bf[srow][sseg * 8] = bv;
        __syncthreads();
        f16x8v af = *(const f16x8v*)&Af[w * 16 + lr][lk * 8];
#pragma unroll
        for (int j = 0; j < 4; j++) {
            f16x8v bf = *(const f16x8v*)&Bf[j * 16 + lr][lk * 8];
            acc[j] = __builtin_amdgcn_mfma_f32_16x16x32_f16(af, bf, acc[j], 0, 0, 0);
        }
    }
#pragma unroll
    for (int r = 0; r < 4; r++) {
        int rg = r0 + w * 16 + lk * 4 + r;
        int tg = target[32 + rg];
        float es = 0.0f;
#pragma unroll
        for (int j = 0; j < 4; j++) {
            int n = v0 + j * 16 + lr;
            float lv = acc[j][r];
            if (n == tg) atomicAdd(&tl[rg], lv);
            es += __expf(lv);
        }
#pragma unroll
        for (int m = 1; m < 16; m <<= 1) es += __shfl_xor(es, m);
        if (lr == 0) atomicAdd(&se[rg], es);
    }
}

// ---------------------------------------------------------------------------
// Persistent scan: 256 WGs x 512 threads = 4 chains x 64 WGs.
// Round-12 encoder: MFMA gate dot on wave 0, double-buffered h staging,
// one barrier per step.  Decoder: round-11 verbatim.
// ---------------------------------------------------------------------------
__global__ __launch_bounds__(512, 2) void scan_kernel(
    const f16* __restrict__ eg,      // [1024][CH][64][32][8]
    const float* __restrict__ dg,    // [64][CH][64][32][8]
    const f16* __restrict__ Wenc,    // [2048][512] rows in permuted col order
    const f16* __restrict__ Wdih,    // [2048][512]
    const f16* __restrict__ Wdhh,    // [2048][512]
    const f16* __restrict__ T2l,     // [512][512]
    const f16* __restrict__ CT2l,    // [512][1024]
    const float* __restrict__ wpt,   // [512]
    f16* __restrict__ h_hist,        // [CH][1089][8][512] slot0 zero, rest sentinel
    f16* __restrict__ q_hist,        // [CH][65][8][512]  slot0 zero, rest sentinel
    f16* __restrict__ ctb,           // [64][CH][8][512]  sentinel-filled
    float* __restrict__ ppart,       // [64][CH][8][64]   sentinel-filled
    f16* __restrict__ dout) {        // [2048][512] f16
    const int bid = blockIdx.x;
    const int chain = bid >> 6;
    const int wg = bid & 63;
    const int tid = threadIdx.x;

    f16* hc = h_hist + (size_t)chain * 1089 * 4096;
    f16* qc = q_hist + (size_t)chain * 65 * 4096;

    __shared__ __align__(16) f16  Ws[32 * 520];    // 33280 B encoder weights
    __shared__ __align__(16) f16  hb[2 * 16 * 520];// 33280 B h staging, dbuf, 16 rows
    __shared__ __align__(16) f16  qst[8 * 520];    //  prev ht staging (decoder)
    __shared__ __align__(16) f16  yst[8 * 520];    //  yt staging (decoder)
    __shared__ __align__(16) f16  ctst[8 * 520];   //  ct staging (decoder)
    __shared__ float part[512];
    __shared__ float zbS[64];
    __shared__ float spart[64 * 9];
    __shared__ float scS[64];
    __shared__ float atwS[64];
    __shared__ float ptS[1];

    const int c  = (tid >> 3) & 31;   // gate col (local)     [decoder]
    const int bq = tid & 7;           // batch (local)        [decoder]
    const int kh = tid >> 8;          // k half               [decoder]
    const int sb = tid >> 6, sj = tid & 63;   // staging: batch row, 16B chunk
    const int au = tid & 7, ab = tid >> 3;    // activation: unit, batch (tid<64)

    // stage encoder weight slice (32 rows x 512) into LDS, 520-f16 padded rows
    {
        int r = tid >> 4, seg = tid & 15;
        const float4* s4 = (const float4*)(Wenc + (size_t)(wg * 32 + r) * 512) + seg * 4;
        float4 a0 = s4[0], a1 = s4[1], a2 = s4[2], a3 = s4[3];
        float4* d4 = (float4*)(Ws + r * 520) + seg * 4;
        d4[0] = a0; d4[1] = a1; d4[2] = a2; d4[3] = a3;
    }
    // zero both h staging buffers (incl. the N-pad rows 8..15)
    {
        const i32x4 Z = {0, 0, 0, 0};
        for (int i = tid; i < 2 * 16 * 520 / 8; i += 512) ((i32x4*)hb)[i] = Z;
    }
    __syncthreads();

    // hoist encoder weight A-fragments: af[m][kk], lane mapping row = l&15,
    // k = (l>>4)*8 (identical to gemm_eg_mfma's verified Af read).
    const int l    = tid & 63;
    const int lr16 = l & 15, lkc = l >> 4;
    f16x8v af[2][16];
#pragma unroll
    for (int m = 0; m < 2; m++)
#pragma unroll
        for (int kk = 0; kk < 16; kk++)
            af[m][kk] = *(const f16x8v*)(Ws + (size_t)(m * 16 + lr16) * 520
                                            + kk * 32 + lkc * 8);

    float creg = 0.0f;                // cell state (tid<64)
    f16 eg4[4] = {(f16)0.0f, (f16)0.0f, (f16)0.0f, (f16)0.0f};
    if (tid < 64) {
#pragma unroll
        for (int g = 0; g < 4; g++)
            eg4[g] = eg[(size_t)chain * 16384 + wg * 256 + (g * 8 + au) * 8 + ab];
    }

    // ---------------- encoder: 1024 steps, ONE barrier each ----------------
    for (int t = 0; t < 1024; t++) {
        f16* hbuf = hb + (t & 1) * (16 * 520);
        {   // poll-stage h[t] (8KB) -> rows 0..7 of hbuf
            i32x4 v = poll16(hc + (size_t)t * 4096 + sb * 512 + sj * 8);
            *((i32x4*)(hbuf + sb * 520) + sj) = v;
        }
        __syncthreads();
        if (tid < 64) {   // wave 0: MFMA gate GEMM + activation + publish
            f32x4v acc0 = {}, acc1 = {};
#pragma unroll
            for (int kk = 0; kk < 16; kk++) {
                f16x8v bf = *(const f16x8v*)(hbuf + (size_t)lr16 * 520
                                                  + kk * 32 + lkc * 8);
                acc0 = __builtin_amdgcn_mfma_f32_16x16x32_f16(af[0][kk], bf, acc0, 0, 0, 0);
                acc1 = __builtin_amdgcn_mfma_f32_16x16x32_f16(af[1][kk], bf, acc1, 0, 0, 0);
            }
            // D: col(gate) = lkc*4 + r (+16 for acc1), batch = lr16 (<8 real)
            if (lr16 < 8) {
#pragma unroll
                for (int r = 0; r < 4; r++) {
                    part[(lkc * 4 + r) * 8 + lr16]      = acc0[r];
                    part[(16 + lkc * 4 + r) * 8 + lr16] = acc1[r];
                }
            }
            float gi = (float)eg4[0] + part[(au) * 8 + ab];
            float gf = (float)eg4[1] + part[(8 + au) * 8 + ab];
            float gg = (float)eg4[2] + part[(16 + au) * 8 + ab];
            float go = (float)eg4[3] + part[(24 + au) * 8 + ab];
            float cc = sigf(gf) * creg + sigf(gi) * tanh_f(gg);
            float hh = sigf(go) * tanh_f(cc);
            creg = cc;
            st_wt_b16(hc + (size_t)(t + 1) * 4096 + ab * 512 + wg * 8 + au, (f16)hh);
            if (t < 1023) {   // prefetch next step's eg (in flight thru staging)
#pragma unroll
                for (int g = 0; g < 4; g++)
                    eg4[g] = eg[((size_t)(t + 1) * 4 + chain) * 16384
                                + wg * 256 + (g * 8 + au) * 8 + ab];
            }
        }
        // waves 1..7 loop straight to polling t+1 into the OTHER buffer;
        // staging of t+2 into this buffer is gated by barrier(t+1), which
        // wave 0 reaches only after finishing its reads here.
    }

    // ---------------- decoder: 64 steps (round-11 verbatim) ----------------
    V8 wregD[32];
    {
        const f16* W1 = Wdih + (size_t)(wg * 32 + c) * 512 + kh * 256;
#pragma unroll
        for (int k8 = 0; k8 < 32; k8++) wregD[k8].f4 = *(const float4*)(W1 + k8 * 8);
    }
    // pre-stage yst = hc[1024] (encoder final h; doubles as hsrc for t=0)
    {
        i32x4 v = poll16(hc + (size_t)1024 * 4096 + sb * 512 + sj * 8);
        *((i32x4*)(yst + sb * 520) + sj) = v;
    }

    for (int t = 0; t < 64; t++) {
        f16* ydst = hc + (size_t)(1025 + t) * 4096;       // yt slot

        // ---- stage A: gates = dg + Wih_h.ht + Whh.h; ht from qst, h from yst ----
        {   // poll-stage qc[t] (8KB) -> qst, full row coverage
            i32x4 v = poll16(qc + (size_t)t * 4096 + sb * 512 + sj * 8);
            *((i32x4*)(qst + sb * 520) + sj) = v;
        }
        __syncthreads();
        {
            float dgv = (kh == 0)
                ? dg[((size_t)t * 4 + chain) * 16384 + wg * 256 + c * 8 + bq] : 0.0f;
            const f16* W2 = Wdhh + (size_t)(wg * 32 + c) * 512 + kh * 256;
            const f16* q0 = qst + bq * 520 + kh * 256;
            const f16* h0 = yst + bq * 520 + kh * 256;
            float a0 = dgv;
#pragma unroll
            for (int k8 = 0; k8 < 32; k8++) {
                V8 w2, x0, y0;
                x0.f4 = *(const float4*)(q0 + k8 * 8);
                w2.f4 = *(const float4*)(W2 + k8 * 8);
                y0.f4 = *(const float4*)(h0 + k8 * 8);
#pragma unroll
                for (int q = 0; q < 4; q++) {
                    a0 = dot2f(wregD[k8].p[q], x0.p[q], a0);
                    a0 = dot2f(w2.p[q], y0.p[q], a0);
                }
            }
            part[tid] = a0;
        }
        __syncthreads();
        if (tid < 64) {
            float gi = part[(au)      * 8 + ab] + part[256 + (au)      * 8 + ab];
            float gf = part[(8 + au)  * 8 + ab] + part[256 + (8 + au)  * 8 + ab];
            float gg = part[(16 + au) * 8 + ab] + part[256 + (16 + au) * 8 + ab];
            float go = part[(24 + au) * 8 + ab] + part[256 + (24 + au) * 8 + ab];
            float cc = sigf(gf) * creg + sigf(gi) * tanh_f(gg);
            float hh = sigf(go) * tanh_f(cc);
            creg = cc;
            st_wt_b16(ydst + ab * 512 + wg * 8 + au, (f16)hh);
        }

        // ---- stage B: poll-stage yt -> yst; z = tanh(yt @ W_ht2tan.T); pt partial ----
        {
            i32x4 v = poll16(ydst + sb * 512 + sj * 8);
            *((i32x4*)(yst + sb * 520) + sj) = v;
        }
        __syncthreads();
        {
            int kq = tid >> 6, zu = (tid >> 3) & 7, zq = tid & 7;
            const f16* Tr = T2l + (size_t)(wg * 8 + zu) * 512 + kq * 64;
            const f16* yr = yst + zq * 520 + kq * 64;
            float s = 0.0f;
#pragma unroll
            for (int k = 0; k < 64; k += 8) {
                V8 aa, bb;
                aa.f4 = *(const float4*)(Tr + k);
                bb.f4 = *(const float4*)(yr + k);
#pragma unroll
                for (int q = 0; q < 4; q++) s = dot2f(aa.p[q], bb.p[q], s);
            }
            part[tid] = s;
        }
        __syncthreads();
        if (tid < 64) {
            float z = 0.0f;
#pragma unroll
            for (int kq = 0; kq < 8; kq++) z += part[kq * 64 + tid];
            zbS[tid] = tanh_f(z);             // zbS[zu*8 + zq]
        }
        __syncthreads();
        if (tid < 8) {
            float pp = 0.0f;
#pragma unroll
            for (int u2 = 0; u2 < 8; u2++) pp += zbS[u2 * 8 + tid] * wpt[wg * 8 + u2];
            st_wt_f32(&ppart[(((size_t)t * 4 + chain) * 8 + tid) * 64 + wg], pp);
        }

        // ---- stage C: local attention (WG wg<8 owns chain-batch wg) ----
        if (wg < 8) {
            const int bb = wg;
            if (tid < 64) {
                const float* pa = ppart + (((size_t)t * 4 + chain) * 8 + bb) * 64 + tid;
                unsigned bits = ld_bypass_u32(pa);
                while (bits == 0xFFFFFFFFu) bits = ld_bypass_u32(pa);
                union { unsigned u; float f; } cv; cv.u = bits;
                float v = cv.f;
#pragma unroll
                for (int off = 32; off > 0; off >>= 1) v += __shfl_down(v, off);
                if (tid == 0) ptS[0] = v;
            }
            __syncthreads();
            float pt = sigf(ptS[0]);
            float center = 1024.0f * pt;
            int ci = (int)floorf(center);
            int left = max(0, ci - 32);
            int right = min(1024, ci + 32);
            int win = right - left;
            int p = tid >> 3, seg = tid & 7;
            if (p < win) {
                const f16* yr = yst + bb * 520 + seg * 64;
                const f16* er = hc + (size_t)(left + p + 1) * 4096 + bb * 512 + seg * 64;
                float s = 0.0f;
#pragma unroll
                for (int k = 0; k < 64; k += 8) {
                    V8 aa, bbv;
                    aa.f4  = *(const float4*)(yr + k);
                    bbv.f4 = *(const float4*)(er + k);
#pragma unroll
                    for (int q = 0; q < 4; q++) s = dot2f(aa.p[q], bbv.p[q], s);
                }
                spart[p * 9 + seg] = s;
            }
            __syncthreads();
            if (tid < 64) {
                float s = -1e30f;
                if (tid < win) {
                    s = 0.0f;
#pragma unroll
                    for (int x = 0; x < 8; x++) s += spart[tid * 9 + x];
                }
                scS[tid] = s;
            }
            __syncthreads();
            float mx = -1e30f;
            for (int q2 = 0; q2 < 64; q2++) mx = fmaxf(mx, scS[q2]);
            float sum = 0.0f;
            for (int q2 = 0; q2 < 64; q2++) sum += __expf(scS[q2] - mx);
            if (tid < 64) {
                float sp = (float)(left + tid) - center;
                float gs = __expf(-(sp * sp) * (1.0f / 512.0f));
                atwS[tid] = (tid < win) ? (__expf(scS[tid] - mx) / sum) * gs : 0.0f;
            }
            __syncthreads();
            {
                int j = tid;   // 0..511
                float a = 0.0f;
                const f16* ebase = hc + (size_t)(left + 1) * 4096 + bb * 512 + j;
                for (int p2 = 0; p2 < win; p2++)
                    a += atwS[p2] * (float)ebase[(size_t)p2 * 4096];
                st_wt_b16(ctb + ((((size_t)t * 4 + chain) * 8 + bb) * 512) + j, (f16)a);
            }
        }

        // ---- stage D: poll-stage ct -> ctst; ht_new = tanh([ct, yt] @ W_ct2ht.T) ----
        {
            i32x4 v = poll16(ctb + (((size_t)t * 4 + chain) * 8 + sb) * 512 + sj * 8);
            *((i32x4*)(ctst + sb * 520) + sj) = v;
        }
        __syncthreads();
        {
            int kq = tid >> 6, du = (tid >> 3) & 7, dq = tid & 7;
            const f16* Cr = CT2l + (size_t)(wg * 8 + du) * 1024 + kq * 128;
            const f16* xr = (kq < 4)
                ? (ctst + dq * 520 + kq * 128)
                : (yst + dq * 520 + (kq - 4) * 128);
            float s = 0.0f;
#pragma unroll 4
            for (int k = 0; k < 128; k += 8) {
                V8 aa, bb;
                aa.f4 = *(const float4*)(Cr + k);
                bb.f4 = *(const float4*)(xr + k);
#pragma unroll
                for (int q = 0; q < 4; q++) s = dot2f(aa.p[q], bb.p[q], s);
            }
            part[tid] = s;
        }
        __syncthreads();
        if (tid < 64) {
            float s = 0.0f;
#pragma unroll
            for (int kq = 0; kq < 8; kq++) s += part[kq * 64 + tid];
            float hv = tanh_f(s);
            int du = tid >> 3, dq = tid & 7;
            st_wt_b16(qc + (size_t)(t + 1) * 4096 + dq * 512 + wg * 8 + du, (f16)hv);
            dout[((size_t)t * 32 + chain * 8 + dq) * 512 + wg * 8 + du] = (f16)hv;
        }
        // no end barrier: stage A(t+1) polls qc[t+1]
    }
}

__global__ void finalize_out(const float* __restrict__ se, const float* __restrict__ tl,
                             const int* __restrict__ target, float* __restrict__ out) {
    int b = threadIdx.x;
    if (b >= 32) return;
    float s = 0.0f;
    for (int t = 0; t < 64; t++) {
        int r = t * 32 + b;
        int tg = target[(t + 1) * 32 + b];
        if (tg != 0) s += tl[r] - logf(se[r]);
    }
    out[b] = s;
}

// ---------------------------------------------------------------------------
extern "C" void kernel_launch(void* const* d_in, const int* in_sizes, int n_in,
                              void* d_out, int out_size, void* d_ws, size_t ws_size,
                              hipStream_t stream) {
    const int*   source   = (const int*)  d_in[0];
    const int*   target   = (const int*)  d_in[1];
    const float* src_emb  = (const float*)d_in[2];
    const float* tar_emb  = (const float*)d_in[3];
    const float* enc_Wih  = (const float*)d_in[4];
    const float* enc_Whh  = (const float*)d_in[5];
    const float* enc_b    = (const float*)d_in[6];
    const float* dec_Wih  = (const float*)d_in[7];
    const float* dec_Whh  = (const float*)d_in[8];
    const float* dec_b    = (const float*)d_in[9];
    const float* W_ht2tan = (const float*)d_in[10];
    const float* W_tan2pt = (const float*)d_in[11];
    const float* W_ct2ht  = (const float*)d_in[12];
    const float* W_final  = (const float*)d_in[13];
    float* out = (float*)d_out;

    char* ws = (char*)d_ws;
    size_t off = 0;
    auto alloc = [&](size_t bytes) -> char* {
        char* p = ws + off;
        off = (off + bytes + 255) & ~(size_t)255;
        return p;
    };
    f16*   h_hist = (f16*)  alloc((size_t)CH * 1089 * 4096 * 2);  // 35.7 MB
    f16*   q_hist = (f16*)  alloc((size_t)CH * 65 * 4096 * 2);
    f16*   ctb    = (f16*)  alloc((size_t)64 * CH * 8 * 512 * 2);
    float* ppart  = (float*)alloc((size_t)64 * CH * 8 * 64 * 4);
    float* se     = (float*)alloc((size_t)2048 * 4);
    float* tl     = (float*)alloc((size_t)2048 * 4);
    f16*   eg     = (f16*)  alloc((size_t)32768 * 2048 * 2);      // 128 MB
    float* dg     = (float*)alloc((size_t)2048 * 2048 * 4);       // 16 MB
    f16*   Wenc   = (f16*)  alloc((size_t)2048 * 512 * 2);
    f16*   Wdih   = (f16*)  alloc((size_t)2048 * 512 * 2);
    f16*   Wdhh   = (f16*)  alloc((size_t)2048 * 512 * 2);
    f16*   T2l    = (f16*)  alloc((size_t)512 * 512 * 2);
    f16*   CT2l   = (f16*)  alloc((size_t)512 * 1024 * 2);
    f16*   dout   = (f16*)  alloc((size_t)2048 * 512 * 2);
    f16*   Wf16   = eg;     // reuse: eg is dead after scan; 33MB <= 128MB

    fill_sentinel<<<2048, 256, 0, stream>>>((i32x4*)h_hist, (i32x4*)q_hist,
                                            (i32x4*)ctb, (i32x4*)ppart, se, tl);
    convert_weights<<<2048, 256, 0, stream>>>(enc_Whh, dec_Wih, dec_Whh, W_ht2tan, W_ct2ht,
                                              Wenc, Wdih, Wdhh, T2l, CT2l);
    gemm_eg_mfma<<<dim3(32, 512), 256, 0, stream>>>(src_emb, source, enc_Wih, enc_b, eg);
    gemm_gather<float><<<dim3(32, 32), 256, 0, stream>>>(tar_emb, target, dec_Wih, 1024,
                                                         dec_b, dg);
    scan_kernel<<<CH * WPC, 512, 0, stream>>>(eg, dg, Wenc, Wdih, Wdhh, T2l, CT2l,
                                              W_tan2pt, h_hist, q_hist, ctb, ppart,
                                              dout);
    convert_wfinal<<<2048, 256, 0, stream>>>(W_final, Wf16);
    proj_lse_mfma<<<dim3(500, 32), 256, 0, stream>>>(dout, Wf16, target, se, tl);
    finalize_out<<<1, 64, 0, stream>>>(se, tl, target, out);
}